// Round 19
// baseline (84.954 us; speedup 1.0000x reference)
//
#include <hip/hip_runtime.h>
#include <cmath>

typedef float  f32x4  __attribute__((ext_vector_type(4)));
typedef __bf16 bf16x8 __attribute__((ext_vector_type(8)));
typedef unsigned int u32x4 __attribute__((ext_vector_type(4)));
typedef unsigned int u32x2 __attribute__((ext_vector_type(2)));
typedef unsigned int   u32;
typedef unsigned short u16;

#define HEAD_DIM 64
#define N_HEADS  25
#define N_KV     5
#define WINDOW   1024
#define N_META   128
#define B_       2
#define T_       2048
#define QB       64
#define NTILES   (T_ / 64)          // 64-key tiles in ws (unchanged)
#define TILE_U32 2048               // 64-key tile: 64 rows x 32 u32 (8 KB)
#define T32_U32  1024               // 32-key tile: 4 KB
// Constant softmax bias: S*0.125*log2e <= (8*1.5)^2*0.125*1.443 ~= 26 (RMSNorm-guaranteed,
// w in [0.5,1.5]). exp2(S-20) <= 64; l <= 6.6e4; min ~= 2^-46 (normal). Scale cancels in O/l.
#define SM_BIAS  (-20.0f)

static __device__ __forceinline__ u16 bf16_bits(float f) {
  __bf16 h = (__bf16)f;
  return __builtin_bit_cast(u16, h);
}
static __device__ __forceinline__ u32 pack2(float lo, float hi) {
  return ((u32)bf16_bits(hi) << 16) | bf16_bits(lo);
}
static __device__ __forceinline__ float fexp2(float x) {
  return __builtin_amdgcn_exp2f(x);    // bare v_exp_f32; exp2(-inf)=0
}
static __device__ __forceinline__ void gload16(const u32* g, u32* l) {
  __builtin_amdgcn_global_load_lds((const __attribute__((address_space(1))) u32*)g,
                                   (__attribute__((address_space(3))) u32*)l, 16, 0, 0);
}

// ---------------- Kernel 1 (merged prep, unchanged from r18): V-tiles + K-rows ---------
// K ws: [b][kvh][tile64][key(64)][seg_phys(8) x 4 u32]; seg_phys = seg_log ^ (key&7)
// V ws: [b][kvh][tile64][d(64)][32 u32]; col c=16a+8b+2g+e at seg (4a+g)^(d&7), slot 2b+e
__global__ __launch_bounds__(256) void prep_kernel(
    const float* __restrict__ k_in, const float* __restrict__ k_w,
    const float* __restrict__ v_in, const int* __restrict__ pos_ids,
    u32* __restrict__ k_ws, u32* __restrict__ v_ws)
{
  const int blk = blockIdx.x;
  const int tid = threadIdx.x;

  if (blk < B_ * N_KV * NTILES) {
    // ---------------- V transpose tile ----------------
    int tile = blk & (NTILES - 1);
    int bk   = blk >> 5;
    int kvh  = bk % N_KV, b = bk / N_KV;
    int t0   = tile * 64;

    __shared__ u16 Tl[64][72];           // [d][key]

    #pragma unroll
    for (int it = 0; it < 4; ++it) {
      int idx = it * 256 + tid;
      int kl = idx >> 4, dq = idx & 15;
      const float4 f = *(const float4*)&v_in[((size_t)(b * T_ + t0 + kl)) * (N_KV * HEAD_DIM) + kvh * HEAD_DIM + dq * 4];
      Tl[dq * 4 + 0][kl] = bf16_bits(f.x);
      Tl[dq * 4 + 1][kl] = bf16_bits(f.y);
      Tl[dq * 4 + 2][kl] = bf16_bits(f.z);
      Tl[dq * 4 + 3][kl] = bf16_bits(f.w);
    }
    __syncthreads();

    u32* outb = v_ws + (size_t)blk * TILE_U32;
    #pragma unroll
    for (int it = 0; it < 8; ++it) {
      int o = it * 256 + tid;
      int d = o >> 5, c = o & 31;
      u32 w = ((u32)Tl[d][2 * c + 1] << 16) | Tl[d][2 * c];
      int a = c >> 4, bs = (c >> 3) & 1, gp = (c >> 1) & 3, e = c & 1;
      int sp = (4 * a + gp) ^ (d & 7);
      outb[d * 32 + sp * 4 + 2 * bs + e] = w;
    }
    return;
  }

  // ---------------- K RMSNorm + RoPE rows ----------------
  int gw   = (((blk - B_ * N_KV * NTILES) * 256 + tid) >> 6);
  int lane = tid & 63;
  if (gw >= B_ * T_ * N_KV) return;
  int kvh = gw % N_KV;
  int bt  = gw / N_KV;

  float x = k_in[(size_t)bt * (N_KV * HEAD_DIM) + kvh * HEAD_DIM + lane];
  float ss = x * x;
  #pragma unroll
  for (int off = 32; off; off >>= 1) ss += __shfl_xor(ss, off);
  float y = k_w[lane] * x * rsqrtf(ss * (1.f / 64.f) + 1e-6f);

  int   pos = pos_ids[bt];
  float ang = (float)pos * powf(10000.f, -(float)(lane & 31) * (1.f / 32.f));
  float c, s;
  sincosf(ang, &s, &c);              // sincosf(x, sin*, cos*)
  float part = __shfl_xor(y, 32);
  float r = (lane < 32) ? (y * c - part * s) : (y * c + part * s);

  u16 mybits = bf16_bits(r);
  u32 pb = (u32)(u16)__shfl_xor((int)mybits, 1);
  u32 w  = (pb << 16) | mybits;
  int b = bt / T_, t = bt % T_;
  if (!(lane & 1)) {
    int c32 = lane >> 1;
    int kl = t & 63, tile = t >> 6;
    int sp = (c32 >> 2) ^ (kl & 7);
    k_ws[(((size_t)(b * N_KV + kvh) * NTILES + tile)) * TILE_U32 + kl * 32 + sp * 4 + (c32 & 3)] = w;
  }
}

// ---------------- Kernel 2: fused MFMA flash attention, KVBLK=32, 16KB LDS -------------
// 32-key tiles halve LDS -> 8 blocks (32 waves) per CU. K sub-tile = contiguous half of
// the 64-key ws tile. V sub-tile s: per d-row one contiguous 64B half at h(d)=s^((d>>2)&1);
// staged with per-lane global addr + linear LDS; read b128 at seg g^(d&3) (k-order == af).
__global__ __launch_bounds__(256, 8) void attn_kernel(
    const float* __restrict__ q_in, const float* __restrict__ q_w,
    const int* __restrict__ pos_ids,
    const u32* __restrict__ kws, const u32* __restrict__ vws,
    float* __restrict__ out)
{
  // XCD-affinity + LPT decode (r14; FETCH 44.8->16.5MB proven).
  const int i  = blockIdx.x;
  const int x  = i & 7, k = i >> 3;
  const int gA = (5 * x) >> 2;
  const int a0 = 200 * x - 160 * gA;
  const int nB = 40 + a0;
  int grp, j_;
  if (k < nB) { grp = gA + 1; j_ = k; }
  else        { grp = gA;     j_ = a0 + (k - nB); }
  const int qt  = 31 - j_ / 5;
  const int hh  = j_ % 5;
  const int b   = grp / 5;
  const int kvh = grp % 5;
  const int h   = kvh * 5 + hh;
  const int qb  = qt * QB;
  const int tid = threadIdx.x, wid = tid >> 6, lane = tid & 63;
  const int l15 = lane & 15, g = lane >> 4;
  const int qrow0 = wid * 16;

  __shared__ u32 Ks[2 * T32_U32];        // 32-key K tiles (buf1 hosts Q rows 0..31 pre-loop)
  __shared__ u32 Vt[2 * T32_U32];        // 32-key V^T tiles (buf1: Q rows 32..63 pre-loop)

  // tile list (32-key tiles): qt<=17: 0..2qt+1; qt>=18: {0..3} U [2qt-32, 2qt+1]
  const int nt      = (qt <= 17) ? (2 * qt + 2) : 38;
  const int shift32 = 2 * qt - 36;               // used when qt >= 18, i2 >= 4

  const size_t kvbase = ((size_t)(b * N_KV + kvh)) * NTILES * TILE_U32;
  const u32* kb = kws + kvbase;
  const u32* vb = vws + kvbase;

  // ---- stage tile32 0 into buf 0 (K half-tile contiguous; V per-lane src, linear LDS) --
  #pragma unroll
  for (int j = 0; j < 2; ++j) {
    int ci = (wid << 1) | j;                     // 0..7: 0-3 K chunks, 4-7 V chunks
    if (ci < 4) {
      gload16(kb + ci * 256 + lane * 4, &Ks[ci * 256]);
    } else {
      int c = ci - 4;
      int d = c * 16 + (lane >> 2), p = lane & 3;
      int hd = (d >> 2) & 1;                     // s=0 for tile 0
      gload16(vb + d * 32 + hd * 16 + p * 4, &Vt[c * 256]);
    }
  }

  // ---- Q staging, 4-rows-parallel (r16): wave wid rows 16wid+4it+g; d = 4*l15..+3 ----
  {
    const int   jbase = (4 * l15) & 31;
    const float r32   = 0.74989420933f;          // 10000^(-1/32)
    float fr[4];
    fr[0] = powf(10000.f, -(float)jbase * (1.f / 32.f));
    fr[1] = fr[0] * r32; fr[2] = fr[1] * r32; fr[3] = fr[2] * r32;

    u32* qstage = ((wid < 2) ? Ks : Vt) + T32_U32;
    const int rbase = (qrow0 & 31);

    const int t0g = b * T_ + qb + qrow0;
    int pos_prev = pos_ids[t0g + g];
    float cc[4], sn[4], c4[4], s4[4];
    #pragma unroll
    for (int e = 0; e < 4; ++e) {
      sincosf((float)pos_prev * fr[e], &sn[e], &cc[e]);   // sincosf(x, sin*, cos*)
      sincosf(4.f * fr[e], &s4[e], &c4[e]);
    }
    const float4 wv = *(const float4*)&q_w[4 * l15];
    #pragma unroll
    for (int it = 0; it < 4; ++it) {
      const int row = 4 * it + g;
      if (it) {
        int pos = pos_ids[t0g + row];
        if (__all(pos == pos_prev + 4)) {
          #pragma unroll
          for (int e = 0; e < 4; ++e) {
            float c2 = cc[e] * c4[e] - sn[e] * s4[e];
            sn[e] = sn[e] * c4[e] + cc[e] * s4[e];
            cc[e] = c2;
          }
        } else {
          #pragma unroll
          for (int e = 0; e < 4; ++e) sincosf((float)pos * fr[e], &sn[e], &cc[e]);
        }
        pos_prev = pos;
      }
      const float4 xv = *(const float4*)&q_in[((size_t)(t0g + row)) * (N_HEADS * HEAD_DIM) + h * HEAD_DIM + 4 * l15];
      float ss = xv.x * xv.x + xv.y * xv.y + xv.z * xv.z + xv.w * xv.w;
      ss += __shfl_xor(ss, 1); ss += __shfl_xor(ss, 2);
      ss += __shfl_xor(ss, 4); ss += __shfl_xor(ss, 8);
      const float rn = rsqrtf(ss * (1.f / 64.f) + 1e-6f);
      float y[4] = {wv.x * xv.x * rn, wv.y * xv.y * rn, wv.z * xv.z * rn, wv.w * xv.w * rn};
      float rv[4];
      #pragma unroll
      for (int e = 0; e < 4; ++e) {
        float part = __shfl_xor(y[e], 8);
        rv[e] = ((l15 < 8) ? (y[e] * cc[e] - part * sn[e])
                           : (y[e] * cc[e] + part * sn[e])) * 0.18033688f;
      }
      u32x2 w2;
      w2.x = pack2(rv[0], rv[1]);
      w2.y = pack2(rv[2], rv[3]);
      *(u32x2*)&qstage[(rbase + row) * 32 + 2 * l15] = w2;
    }
  }
  __syncthreads();                       // tile0 loads drained + Q rows visible

  bf16x8 qf[2];
  {
    const u32* qstage = ((wid < 2) ? Ks : Vt) + T32_U32;
    const int rbase = (qrow0 & 31);
    #pragma unroll
    for (int ks = 0; ks < 2; ++ks)
      qf[ks] = *(const bf16x8*)&qstage[(rbase + l15) * 32 + 16 * ks + 4 * g];
  }
  __syncthreads();                       // qf reads done before buf1 is overwritten

  float l_part = 0.f;                    // per-lane partial of l (g-reduce deferred)
  f32x4 acc_o[4];
  #pragma unroll
  for (int mt = 0; mt < 4; ++mt) acc_o[mt] = (f32x4)(0.f);

  const int q_abs = qb + qrow0 + l15;

  int buf = 0;
  for (int i2 = 0; i2 < nt; ++i2) {
    // ---- prefetch next 32-key tile into buf^1 ----
    if (i2 + 1 < nt) {
      int tn = (qt <= 17 || i2 + 1 < 4) ? (i2 + 1) : (i2 + 1 + shift32);
      u32* kd = &Ks[(buf ^ 1) * T32_U32];
      u32* vd = &Vt[(buf ^ 1) * T32_U32];
      #pragma unroll
      for (int j = 0; j < 2; ++j) {
        int ci = (wid << 1) | j;
        if (ci < 4) {
          gload16(kb + (size_t)tn * T32_U32 + ci * 256 + lane * 4, kd + ci * 256);
        } else {
          int c = ci - 4;
          int d = c * 16 + (lane >> 2), p = lane & 3;
          int hd = (tn & 1) ^ ((d >> 2) & 1);
          gload16(vb + (size_t)(tn >> 1) * TILE_U32 + d * 32 + hd * 16 + p * 4, vd + c * 256);
        }
      }
    }
    const int k0 = ((qt <= 17 || i2 < 4) ? i2 : i2 + shift32) << 5;

    // ---- S^T - 20 for 32 keys x 16 queries (bias in MFMA C-init) ----
    f32x4 accs[2];
    accs[0] = (f32x4)(SM_BIAS);
    accs[1] = (f32x4)(SM_BIAS);
    #pragma unroll
    for (int ks = 0; ks < 2; ++ks) {
      #pragma unroll
      for (int mt = 0; mt < 2; ++mt) {
        bf16x8 kf = *(const bf16x8*)&Ks[buf * T32_U32 + (16 * mt + l15) * 32 + (((4 * ks + g) ^ (l15 & 7)) << 2)];
        accs[mt] = __builtin_amdgcn_mfma_f32_16x16x32_bf16(kf, qf[ks], accs[mt], 0, 0, 0);
      }
    }

    // ---- mask boundary tiles: diagonal (last 2); window-entry i2=4,5 when qt>=18 ----
    const bool do_mask = (i2 >= nt - 2) || (qt >= 18 && (i2 == 4 || i2 == 5));
    if (do_mask) {
      #pragma unroll
      for (int mt = 0; mt < 2; ++mt)
        #pragma unroll
        for (int rg = 0; rg < 4; ++rg) {
          int key = k0 + 16 * mt + 4 * g + rg;
          bool ok = (key <= q_abs) && ((key >= q_abs - (WINDOW - 1)) || (key < N_META));
          accs[mt][rg] = ok ? accs[mt][rg] : -INFINITY;
        }
    }
    float rsum = 0.f;
    #pragma unroll
    for (int mt = 0; mt < 2; ++mt)
      #pragma unroll
      for (int rg = 0; rg < 4; ++rg) {
        float pi = fexp2(accs[mt][rg]);          // exp2(-inf) = 0 for masked
        accs[mt][rg] = pi;
        rsum += pi;
      }
    l_part += rsum;

    // ---- O += P·V (one K=32 MFMA pass; vf b128 at seg g^(d&3)) ----
    {
      u32x4 aw;
      aw.x = pack2(accs[0][0], accs[0][1]);
      aw.y = pack2(accs[0][2], accs[0][3]);
      aw.z = pack2(accs[1][0], accs[1][1]);
      aw.w = pack2(accs[1][2], accs[1][3]);
      bf16x8 af = __builtin_bit_cast(bf16x8, aw);
      #pragma unroll
      for (int mt2 = 0; mt2 < 4; ++mt2) {
        bf16x8 vf = *(const bf16x8*)&Vt[buf * T32_U32 + (16 * mt2 + l15) * 16 + ((g ^ (l15 & 3)) << 2)];
        acc_o[mt2] = __builtin_amdgcn_mfma_f32_16x16x32_bf16(af, vf, acc_o[mt2], 0, 0, 0);
      }
    }

    __syncthreads();     // drains vmcnt (next tile landed) + all waves done with buf
    buf ^= 1;
  }

  // ---- epilogue: reduce l across g-groups once, divide, store ----
  float lsum = l_part;
  lsum += __shfl_xor(lsum, 16);
  lsum += __shfl_xor(lsum, 32);
  float l4[4];
  #pragma unroll
  for (int rg = 0; rg < 4; ++rg) l4[rg] = __shfl(lsum, 4 * g + rg);
  #pragma unroll
  for (int mt2 = 0; mt2 < 4; ++mt2)
    #pragma unroll
    for (int rg = 0; rg < 4; ++rg) {
      int t = qb + qrow0 + 4 * g + rg;
      out[((size_t)(b * T_ + t)) * (N_HEADS * HEAD_DIM) + h * HEAD_DIM + 16 * mt2 + l15] =
          acc_o[mt2][rg] / l4[rg];
    }
}

extern "C" void kernel_launch(void* const* d_in, const int* in_sizes, int n_in,
                              void* d_out, int out_size, void* d_ws, size_t ws_size,
                              hipStream_t stream) {
  const float* q   = (const float*)d_in[0];
  const float* k   = (const float*)d_in[1];
  const float* v   = (const float*)d_in[2];
  const float* qw  = (const float*)d_in[3];
  const float* kw  = (const float*)d_in[4];
  const int*   pos = (const int*)d_in[5];

  u32* kp = (u32*)d_ws;                                    // 2.62 MB
  u32* vp = kp + (size_t)B_ * N_KV * NTILES * TILE_U32;    // 2.62 MB
  float* outp = (float*)d_out;

  // merged prep: 320 V-tile blocks + 5120 K-row blocks in one launch
  prep_kernel<<<B_ * N_KV * NTILES + 5120, 256, 0, stream>>>(k, kw, v, pos, kp, vp);
  attn_kernel<<<1600, 256, 0, stream>>>(q, qw, pos, kp, vp, outp);
}

// Round 20
// 58.215 us; speedup vs baseline: 1.4593x; 1.4593x over previous
//
#include <hip/hip_runtime.h>
#include <cmath>

typedef float  f32x4  __attribute__((ext_vector_type(4)));
typedef __bf16 bf16x8 __attribute__((ext_vector_type(8)));
typedef unsigned int u32x4 __attribute__((ext_vector_type(4)));
typedef unsigned int u32x2 __attribute__((ext_vector_type(2)));
typedef unsigned int   u32;
typedef unsigned short u16;

#define HEAD_DIM 64
#define N_HEADS  25
#define N_KV     5
#define WINDOW   1024
#define N_META   128
#define B_       2
#define T_       2048
#define QB       64
#define NTILES   (T_ / 64)
#define TILE_U32 2048               // 64 rows x 32 u32 (8 KB)
// Constant softmax bias: S*0.125*log2e <= (8*1.5)^2*0.125*1.443 ~= 26 (RMSNorm-guaranteed,
// w in [0.5,1.5]). exp2(S-20) <= 64; l <= 6.6e4; min ~= 2^-46 (normal). Scale cancels in O/l.
#define SM_BIAS  (-20.0f)

static __device__ __forceinline__ u16 bf16_bits(float f) {
  __bf16 h = (__bf16)f;
  return __builtin_bit_cast(u16, h);
}
static __device__ __forceinline__ u32 pack2(float lo, float hi) {
  return ((u32)bf16_bits(hi) << 16) | bf16_bits(lo);
}
static __device__ __forceinline__ float fexp2(float x) {
  return __builtin_amdgcn_exp2f(x);    // bare v_exp_f32; exp2(-inf)=0
}
static __device__ __forceinline__ void gload16(const u32* g, u32* l) {
  __builtin_amdgcn_global_load_lds((const __attribute__((address_space(1))) u32*)g,
                                   (__attribute__((address_space(3))) u32*)l, 16, 0, 0);
}

// ---------------- Kernel 1 (merged prep): V-tiles (blk<320) + K-rows (blk>=320) --------
// K ws: [b][kvh][tile][key(64)][seg_phys(8) x 4 u32]; seg_phys = seg_log ^ (key&7)
// V ws: [b][kvh][tile][d(64)][32 u32]; col c=16a+8b+2g+e at seg (4a+g)^(d&7), slot 2b+e
__global__ __launch_bounds__(256) void prep_kernel(
    const float* __restrict__ k_in, const float* __restrict__ k_w,
    const float* __restrict__ v_in, const int* __restrict__ pos_ids,
    u32* __restrict__ k_ws, u32* __restrict__ v_ws)
{
  const int blk = blockIdx.x;
  const int tid = threadIdx.x;

  if (blk < B_ * N_KV * NTILES) {
    // ---------------- V transpose tile ----------------
    int tile = blk & (NTILES - 1);
    int bk   = blk >> 5;
    int kvh  = bk % N_KV, b = bk / N_KV;
    int t0   = tile * 64;

    __shared__ u16 Tl[64][72];           // [d][key]

    #pragma unroll
    for (int it = 0; it < 4; ++it) {
      int idx = it * 256 + tid;
      int kl = idx >> 4, dq = idx & 15;
      const float4 f = *(const float4*)&v_in[((size_t)(b * T_ + t0 + kl)) * (N_KV * HEAD_DIM) + kvh * HEAD_DIM + dq * 4];
      Tl[dq * 4 + 0][kl] = bf16_bits(f.x);
      Tl[dq * 4 + 1][kl] = bf16_bits(f.y);
      Tl[dq * 4 + 2][kl] = bf16_bits(f.z);
      Tl[dq * 4 + 3][kl] = bf16_bits(f.w);
    }
    __syncthreads();

    u32* outb = v_ws + (size_t)blk * TILE_U32;
    #pragma unroll
    for (int it = 0; it < 8; ++it) {
      int o = it * 256 + tid;
      int d = o >> 5, c = o & 31;
      u32 w = ((u32)Tl[d][2 * c + 1] << 16) | Tl[d][2 * c];
      int a = c >> 4, bs = (c >> 3) & 1, gp = (c >> 1) & 3, e = c & 1;
      int sp = (4 * a + gp) ^ (d & 7);
      outb[d * 32 + sp * 4 + 2 * bs + e] = w;
    }
    return;
  }

  // ---------------- K RMSNorm + RoPE rows ----------------
  int gw   = (((blk - B_ * N_KV * NTILES) * 256 + tid) >> 6);
  int lane = tid & 63;
  if (gw >= B_ * T_ * N_KV) return;
  int kvh = gw % N_KV;
  int bt  = gw / N_KV;

  float x = k_in[(size_t)bt * (N_KV * HEAD_DIM) + kvh * HEAD_DIM + lane];
  float ss = x * x;
  #pragma unroll
  for (int off = 32; off; off >>= 1) ss += __shfl_xor(ss, off);
  float y = k_w[lane] * x * rsqrtf(ss * (1.f / 64.f) + 1e-6f);

  int   pos = pos_ids[bt];
  float ang = (float)pos * powf(10000.f, -(float)(lane & 31) * (1.f / 32.f));
  float c, s;
  sincosf(ang, &s, &c);              // sincosf(x, sin*, cos*)
  float part = __shfl_xor(y, 32);
  float r = (lane < 32) ? (y * c - part * s) : (y * c + part * s);

  u16 mybits = bf16_bits(r);
  u32 pb = (u32)(u16)__shfl_xor((int)mybits, 1);
  u32 w  = (pb << 16) | mybits;
  int b = bt / T_, t = bt % T_;
  if (!(lane & 1)) {
    int c32 = lane >> 1;
    int kl = t & 63, tile = t >> 6;
    int sp = (c32 >> 2) ^ (kl & 7);
    k_ws[(((size_t)(b * N_KV + kvh) * NTILES + tile)) * TILE_U32 + kl * 32 + sp * 4 + (c32 & 3)] = w;
  }
}

// ---------------- Kernel 2: fused MFMA flash attention (r18 + l-by-MFMA) ---------------
__global__ __launch_bounds__(256, 4) void attn_kernel(
    const float* __restrict__ q_in, const float* __restrict__ q_w,
    const int* __restrict__ pos_ids,
    const u32* __restrict__ kws, const u32* __restrict__ vws,
    float* __restrict__ out)
{
  // XCD-affinity + LPT decode (r14; FETCH 44.8->16.5MB proven).
  const int i  = blockIdx.x;
  const int x  = i & 7, k = i >> 3;
  const int gA = (5 * x) >> 2;
  const int a0 = 200 * x - 160 * gA;
  const int nB = 40 + a0;
  int grp, j_;
  if (k < nB) { grp = gA + 1; j_ = k; }
  else        { grp = gA;     j_ = a0 + (k - nB); }
  const int qt  = 31 - j_ / 5;
  const int hh  = j_ % 5;
  const int b   = grp / 5;
  const int kvh = grp % 5;
  const int h   = kvh * 5 + hh;
  const int qb  = qt * QB;
  const int tid = threadIdx.x, wid = tid >> 6, lane = tid & 63;
  const int l15 = lane & 15, g = lane >> 4;
  const int qrow0 = wid * 16;

  __shared__ u32 Ks[2 * TILE_U32];       // K tiles (buf1 doubles as Q staging pre-loop)
  __shared__ u32 Vt[2 * TILE_U32];       // V^T tiles

  const int nt    = (qt <= 18) ? (qt + 1) : 19;
  const int shift = qt - 18;

  const size_t kvbase = ((size_t)(b * N_KV + kvh)) * NTILES * TILE_U32;
  const u32* kb = kws + kvbase;
  const u32* vb = vws + kvbase;

  // ---- issue tile-0 staging first (hides under Q-staging compute) ----
  #pragma unroll
  for (int j = 0; j < 4; ++j) {
    int ci = (wid << 2) | j;
    if (ci < 8) gload16(kb + ci * 256 + lane * 4, &Ks[ci * 256]);
    else        gload16(vb + (ci - 8) * 256 + lane * 4, &Vt[(ci - 8) * 256]);
  }

  // ---- Q staging, 4-rows-parallel: lane (g,l15) does row 4*it+g, d = 4*l15..4*l15+3 ----
  {
    const int   jbase = (4 * l15) & 31;
    const float r32   = 0.74989420933f;            // 10000^(-1/32)
    float fr[4];
    fr[0] = powf(10000.f, -(float)jbase * (1.f / 32.f));
    fr[1] = fr[0] * r32; fr[2] = fr[1] * r32; fr[3] = fr[2] * r32;

    const int t0g = b * T_ + qb + qrow0;
    int pos_prev = pos_ids[t0g + g];
    float cc[4], sn[4], c4[4], s4[4];
    #pragma unroll
    for (int e = 0; e < 4; ++e) {
      sincosf((float)pos_prev * fr[e], &sn[e], &cc[e]);   // sincosf(x, sin*, cos*)
      sincosf(4.f * fr[e], &s4[e], &c4[e]);
    }
    const float4 wv = *(const float4*)&q_w[4 * l15];
    #pragma unroll
    for (int it = 0; it < 4; ++it) {
      const int row = 4 * it + g;
      if (it) {
        int pos = pos_ids[t0g + row];
        if (__all(pos == pos_prev + 4)) {
          #pragma unroll
          for (int e = 0; e < 4; ++e) {
            float c2 = cc[e] * c4[e] - sn[e] * s4[e];
            sn[e] = sn[e] * c4[e] + cc[e] * s4[e];
            cc[e] = c2;
          }
        } else {
          #pragma unroll
          for (int e = 0; e < 4; ++e) sincosf((float)pos * fr[e], &sn[e], &cc[e]);
        }
        pos_prev = pos;
      }
      const float4 xv = *(const float4*)&q_in[((size_t)(t0g + row)) * (N_HEADS * HEAD_DIM) + h * HEAD_DIM + 4 * l15];
      float ss = xv.x * xv.x + xv.y * xv.y + xv.z * xv.z + xv.w * xv.w;
      ss += __shfl_xor(ss, 1); ss += __shfl_xor(ss, 2);
      ss += __shfl_xor(ss, 4); ss += __shfl_xor(ss, 8);
      const float rn = rsqrtf(ss * (1.f / 64.f) + 1e-6f);
      float y[4] = {wv.x * xv.x * rn, wv.y * xv.y * rn, wv.z * xv.z * rn, wv.w * xv.w * rn};
      float rv[4];
      #pragma unroll
      for (int e = 0; e < 4; ++e) {
        float part = __shfl_xor(y[e], 8);
        rv[e] = ((l15 < 8) ? (y[e] * cc[e] - part * sn[e])
                           : (y[e] * cc[e] + part * sn[e])) * 0.18033688f;
      }
      u32x2 w2;
      w2.x = pack2(rv[0], rv[1]);
      w2.y = pack2(rv[2], rv[3]);
      *(u32x2*)&Ks[TILE_U32 + (qrow0 + row) * 32 + 2 * l15] = w2;
    }
  }
  __syncthreads();                       // tile0 loads drained + Q rows visible

  bf16x8 qf[2];
  #pragma unroll
  for (int ks = 0; ks < 2; ++ks)
    qf[ks] = *(const bf16x8*)&Ks[TILE_U32 + (qrow0 + l15) * 32 + 16 * ks + 4 * g];
  __syncthreads();                       // all qf reads done before buf1 is overwritten

  f32x4 acc_o[4];
  #pragma unroll
  for (int mt = 0; mt < 4; ++mt) acc_o[mt] = (f32x4)(0.f);
  f32x4 acc_l = (f32x4)(0.f);            // l by MFMA: P x ones -> row q, replicated cols

  // ones B-operand (bf16 1.0 x8), built from constant bits
  u32x4 onesw;
  onesw.x = 0x3F803F80u; onesw.y = 0x3F803F80u; onesw.z = 0x3F803F80u; onesw.w = 0x3F803F80u;
  const bf16x8 vones = __builtin_bit_cast(bf16x8, onesw);

  const int q_abs = qb + qrow0 + l15;

  int buf = 0;
  for (int i2 = 0; i2 < nt; ++i2) {
    // ---- prefetch next tile into buf^1 ----
    if (i2 + 1 < nt) {
      int tn = (qt <= 18 || i2 + 1 < 2) ? (i2 + 1) : (i2 + 1 + shift);
      const u32* kt = kb + (size_t)tn * TILE_U32;
      const u32* vt = vb + (size_t)tn * TILE_U32;
      u32* kd = &Ks[(buf ^ 1) * TILE_U32];
      u32* vd = &Vt[(buf ^ 1) * TILE_U32];
      #pragma unroll
      for (int j = 0; j < 4; ++j) {
        int ci = (wid << 2) | j;
        if (ci < 8) gload16(kt + ci * 256 + lane * 4, kd + ci * 256);
        else        gload16(vt + (ci - 8) * 256 + lane * 4, vd + (ci - 8) * 256);
      }
    }
    const int k0 = ((qt <= 18 || i2 < 2) ? i2 : i2 + shift) << 6;

    // ---- S^T - 20 = K·Q^T + C(-20)  (bias folded into MFMA C-init) ----
    f32x4 accs[4];
    #pragma unroll
    for (int mt = 0; mt < 4; ++mt) accs[mt] = (f32x4)(SM_BIAS);
    #pragma unroll
    for (int ks = 0; ks < 2; ++ks) {
      #pragma unroll
      for (int mt = 0; mt < 4; ++mt) {
        bf16x8 kf = *(const bf16x8*)&Ks[buf * TILE_U32 + (16 * mt + l15) * 32 + (((4 * ks + g) ^ (l15 & 7)) << 2)];
        accs[mt] = __builtin_amdgcn_mfma_f32_16x16x32_bf16(kf, qf[ks], accs[mt], 0, 0, 0);
      }
    }

    // ---- mask boundary tiles, then P = exp2(S - 20) directly (no max tracking) ----
    const bool do_mask = (i2 == nt - 1) || (qt >= 18 && i2 == 2);
    if (do_mask) {
      #pragma unroll
      for (int mt = 0; mt < 4; ++mt)
        #pragma unroll
        for (int rg = 0; rg < 4; ++rg) {
          int key = k0 + 16 * mt + 4 * g + rg;
          bool ok = (key <= q_abs) && ((key >= q_abs - (WINDOW - 1)) || (key < N_META));
          accs[mt][rg] = ok ? accs[mt][rg] : -INFINITY;
        }
    }
    #pragma unroll
    for (int mt = 0; mt < 4; ++mt)
      #pragma unroll
      for (int rg = 0; rg < 4; ++rg)
        accs[mt][rg] = fexp2(accs[mt][rg]);      // exp2(-inf) = 0 for masked

    // ---- O += P·V, l += P·1 (both by MFMA; P in-register, permuted-K order) ----
    #pragma unroll
    for (int ks2 = 0; ks2 < 2; ++ks2) {
      const int m0 = 2 * ks2, m1 = 2 * ks2 + 1;
      u32x4 aw;
      aw.x = pack2(accs[m0][0], accs[m0][1]);
      aw.y = pack2(accs[m0][2], accs[m0][3]);
      aw.z = pack2(accs[m1][0], accs[m1][1]);
      aw.w = pack2(accs[m1][2], accs[m1][3]);
      bf16x8 af = __builtin_bit_cast(bf16x8, aw);
      acc_l = __builtin_amdgcn_mfma_f32_16x16x32_bf16(af, vones, acc_l, 0, 0, 0);
      #pragma unroll
      for (int mt2 = 0; mt2 < 4; ++mt2) {
        bf16x8 vf = *(const bf16x8*)&Vt[buf * TILE_U32 + (16 * mt2 + l15) * 32 + (((4 * ks2 + g) ^ (l15 & 7)) << 2)];
        acc_o[mt2] = __builtin_amdgcn_mfma_f32_16x16x32_bf16(af, vf, acc_o[mt2], 0, 0, 0);
      }
    }

    __syncthreads();     // drains vmcnt (next tile landed) + all waves done with buf
    buf ^= 1;
  }

  // ---- epilogue: l4[rg] = acc_l[rg] directly (row q'=4g+rg, replicated over cols) ----
  #pragma unroll
  for (int mt2 = 0; mt2 < 4; ++mt2)
    #pragma unroll
    for (int rg = 0; rg < 4; ++rg) {
      int t = qb + qrow0 + 4 * g + rg;
      out[((size_t)(b * T_ + t)) * (N_HEADS * HEAD_DIM) + h * HEAD_DIM + 16 * mt2 + l15] =
          acc_o[mt2][rg] / acc_l[rg];
    }
}

extern "C" void kernel_launch(void* const* d_in, const int* in_sizes, int n_in,
                              void* d_out, int out_size, void* d_ws, size_t ws_size,
                              hipStream_t stream) {
  const float* q   = (const float*)d_in[0];
  const float* k   = (const float*)d_in[1];
  const float* v   = (const float*)d_in[2];
  const float* qw  = (const float*)d_in[3];
  const float* kw  = (const float*)d_in[4];
  const int*   pos = (const int*)d_in[5];

  u32* kp = (u32*)d_ws;                                    // 2.62 MB
  u32* vp = kp + (size_t)B_ * N_KV * NTILES * TILE_U32;    // 2.62 MB
  float* outp = (float*)d_out;

  // merged prep: 320 V-tile blocks + 5120 K-row blocks in one launch
  prep_kernel<<<B_ * N_KV * NTILES + 5120, 256, 0, stream>>>(k, kw, v, pos, kp, vp);
  attn_kernel<<<1600, 256, 0, stream>>>(q, qw, pos, kp, vp, outp);
}

// Round 21
// 56.541 us; speedup vs baseline: 1.5025x; 1.0296x over previous
//
#include <hip/hip_runtime.h>
#include <cmath>

typedef float  f32x4  __attribute__((ext_vector_type(4)));
typedef __bf16 bf16x8 __attribute__((ext_vector_type(8)));
typedef unsigned int u32x4 __attribute__((ext_vector_type(4)));
typedef unsigned int u32x2 __attribute__((ext_vector_type(2)));
typedef unsigned int   u32;
typedef unsigned short u16;

#define HEAD_DIM 64
#define N_HEADS  25
#define N_KV     5
#define WINDOW   1024
#define N_META   128
#define B_       2
#define T_       2048
#define QB       64
#define NTILES   (T_ / 64)
#define TILE_U32 2048               // 64 rows x 32 u32 (8 KB)
// Constant softmax bias: S*0.125*log2e <= (8*1.5)^2*0.125*1.443 ~= 26 (RMSNorm-guaranteed,
// w in [0.5,1.5]). exp2(S-20) <= 64; l <= 6.6e4; min ~= 2^-46 (normal). Scale cancels in O/l.
#define SM_BIAS  (-20.0f)

static __device__ __forceinline__ u16 bf16_bits(float f) {
  __bf16 h = (__bf16)f;
  return __builtin_bit_cast(u16, h);
}
static __device__ __forceinline__ u32 pack2(float lo, float hi) {
  return ((u32)bf16_bits(hi) << 16) | bf16_bits(lo);
}
static __device__ __forceinline__ float fexp2(float x) {
  return __builtin_amdgcn_exp2f(x);    // bare v_exp_f32; exp2(-inf)=0
}
static __device__ __forceinline__ void gload16(const u32* g, u32* l) {
  __builtin_amdgcn_global_load_lds((const __attribute__((address_space(1))) u32*)g,
                                   (__attribute__((address_space(3))) u32*)l, 16, 0, 0);
}

// ---------------- Kernel 1 (merged prep): V-tiles (blk<320) + K-rows (blk>=320) --------
// K ws: [b][kvh][tile][key(64)][seg_phys(8) x 4 u32]; seg_phys = seg_log ^ (key&7)
// V ws: [b][kvh][tile][d(64)][32 u32]; col c=16a+8b+2g+e at seg (4a+g)^(d&7), slot 2b+e
__global__ __launch_bounds__(256) void prep_kernel(
    const float* __restrict__ k_in, const float* __restrict__ k_w,
    const float* __restrict__ v_in, const int* __restrict__ pos_ids,
    u32* __restrict__ k_ws, u32* __restrict__ v_ws)
{
  const int blk = blockIdx.x;
  const int tid = threadIdx.x;

  if (blk < B_ * N_KV * NTILES) {
    // ---------------- V transpose tile ----------------
    int tile = blk & (NTILES - 1);
    int bk   = blk >> 5;
    int kvh  = bk % N_KV, b = bk / N_KV;
    int t0   = tile * 64;

    __shared__ u16 Tl[64][72];           // [d][key]

    #pragma unroll
    for (int it = 0; it < 4; ++it) {
      int idx = it * 256 + tid;
      int kl = idx >> 4, dq = idx & 15;
      const float4 f = *(const float4*)&v_in[((size_t)(b * T_ + t0 + kl)) * (N_KV * HEAD_DIM) + kvh * HEAD_DIM + dq * 4];
      Tl[dq * 4 + 0][kl] = bf16_bits(f.x);
      Tl[dq * 4 + 1][kl] = bf16_bits(f.y);
      Tl[dq * 4 + 2][kl] = bf16_bits(f.z);
      Tl[dq * 4 + 3][kl] = bf16_bits(f.w);
    }
    __syncthreads();

    u32* outb = v_ws + (size_t)blk * TILE_U32;
    #pragma unroll
    for (int it = 0; it < 8; ++it) {
      int o = it * 256 + tid;
      int d = o >> 5, c = o & 31;
      u32 w = ((u32)Tl[d][2 * c + 1] << 16) | Tl[d][2 * c];
      int a = c >> 4, bs = (c >> 3) & 1, gp = (c >> 1) & 3, e = c & 1;
      int sp = (4 * a + gp) ^ (d & 7);
      outb[d * 32 + sp * 4 + 2 * bs + e] = w;
    }
    return;
  }

  // ---------------- K RMSNorm + RoPE rows ----------------
  int gw   = (((blk - B_ * N_KV * NTILES) * 256 + tid) >> 6);
  int lane = tid & 63;
  if (gw >= B_ * T_ * N_KV) return;
  int kvh = gw % N_KV;
  int bt  = gw / N_KV;

  float x = k_in[(size_t)bt * (N_KV * HEAD_DIM) + kvh * HEAD_DIM + lane];
  float ss = x * x;
  #pragma unroll
  for (int off = 32; off; off >>= 1) ss += __shfl_xor(ss, off);
  float y = k_w[lane] * x * rsqrtf(ss * (1.f / 64.f) + 1e-6f);

  int   pos = pos_ids[bt];
  float ang = (float)pos * powf(10000.f, -(float)(lane & 31) * (1.f / 32.f));
  float c, s;
  sincosf(ang, &s, &c);              // sincosf(x, sin*, cos*)
  float part = __shfl_xor(y, 32);
  float r = (lane < 32) ? (y * c - part * s) : (y * c + part * s);

  u16 mybits = bf16_bits(r);
  u32 pb = (u32)(u16)__shfl_xor((int)mybits, 1);
  u32 w  = (pb << 16) | mybits;
  int b = bt / T_, t = bt % T_;
  if (!(lane & 1)) {
    int c32 = lane >> 1;
    int kl = t & 63, tile = t >> 6;
    int sp = (c32 >> 2) ^ (kl & 7);
    k_ws[(((size_t)(b * N_KV + kvh) * NTILES + tile)) * TILE_U32 + kl * 32 + sp * 4 + (c32 & 3)] = w;
  }
}

// ---------------- Kernel 2: fused MFMA flash attention (24KB LDS: K dbuf + V single) ---
// V(i+1) issued AFTER end-barrier of tile i (all waves past PV(i) -> overwrite safe);
// drained by the mid-tile barrier of tile i+1 (~700cyc later, >= L2 latency). K prefetch
// as before (issued at tile start, drained by mid-barrier). 24KB -> 6 blocks/CU.
__global__ __launch_bounds__(256, 4) void attn_kernel(
    const float* __restrict__ q_in, const float* __restrict__ q_w,
    const int* __restrict__ pos_ids,
    const u32* __restrict__ kws, const u32* __restrict__ vws,
    float* __restrict__ out)
{
  // XCD-affinity + LPT decode (r14; FETCH 44.8->16.5MB proven).
  const int i  = blockIdx.x;
  const int x  = i & 7, k = i >> 3;
  const int gA = (5 * x) >> 2;
  const int a0 = 200 * x - 160 * gA;
  const int nB = 40 + a0;
  int grp, j_;
  if (k < nB) { grp = gA + 1; j_ = k; }
  else        { grp = gA;     j_ = a0 + (k - nB); }
  const int qt  = 31 - j_ / 5;
  const int hh  = j_ % 5;
  const int b   = grp / 5;
  const int kvh = grp % 5;
  const int h   = kvh * 5 + hh;
  const int qb  = qt * QB;
  const int tid = threadIdx.x, wid = tid >> 6, lane = tid & 63;
  const int l15 = lane & 15, g = lane >> 4;
  const int qrow0 = wid * 16;

  __shared__ u32 Ks[2 * TILE_U32];       // K tiles, double-buffered (buf1 = Q staging pre-loop)
  __shared__ u32 Vt[TILE_U32];           // V^T tile, single-buffered

  const int nt    = (qt <= 18) ? (qt + 1) : 19;
  const int shift = qt - 18;

  const size_t kvbase = ((size_t)(b * N_KV + kvh)) * NTILES * TILE_U32;
  const u32* kb = kws + kvbase;
  const u32* vb = vws + kvbase;

  // ---- prologue: issue K(0)->Ks buf0 and V(0)->Vt (hidden under Q staging) ----
  #pragma unroll
  for (int j = 0; j < 4; ++j) {
    int ci = (wid << 2) | j;
    if (ci < 8) gload16(kb + ci * 256 + lane * 4, &Ks[ci * 256]);
    else        gload16(vb + (ci - 8) * 256 + lane * 4, &Vt[(ci - 8) * 256]);
  }

  // ---- Q staging, 4-rows-parallel: lane (g,l15) does row 4*it+g, d = 4*l15..4*l15+3 ----
  {
    const int   jbase = (4 * l15) & 31;
    const float r32   = 0.74989420933f;            // 10000^(-1/32)
    float fr[4];
    fr[0] = powf(10000.f, -(float)jbase * (1.f / 32.f));
    fr[1] = fr[0] * r32; fr[2] = fr[1] * r32; fr[3] = fr[2] * r32;

    const int t0g = b * T_ + qb + qrow0;
    int pos_prev = pos_ids[t0g + g];
    float cc[4], sn[4], c4[4], s4[4];
    #pragma unroll
    for (int e = 0; e < 4; ++e) {
      sincosf((float)pos_prev * fr[e], &sn[e], &cc[e]);   // sincosf(x, sin*, cos*)
      sincosf(4.f * fr[e], &s4[e], &c4[e]);
    }
    const float4 wv = *(const float4*)&q_w[4 * l15];
    #pragma unroll
    for (int it = 0; it < 4; ++it) {
      const int row = 4 * it + g;
      if (it) {
        int pos = pos_ids[t0g + row];
        if (__all(pos == pos_prev + 4)) {
          #pragma unroll
          for (int e = 0; e < 4; ++e) {
            float c2 = cc[e] * c4[e] - sn[e] * s4[e];
            sn[e] = sn[e] * c4[e] + cc[e] * s4[e];
            cc[e] = c2;
          }
        } else {
          #pragma unroll
          for (int e = 0; e < 4; ++e) sincosf((float)pos * fr[e], &sn[e], &cc[e]);
        }
        pos_prev = pos;
      }
      const float4 xv = *(const float4*)&q_in[((size_t)(t0g + row)) * (N_HEADS * HEAD_DIM) + h * HEAD_DIM + 4 * l15];
      float ss = xv.x * xv.x + xv.y * xv.y + xv.z * xv.z + xv.w * xv.w;
      ss += __shfl_xor(ss, 1); ss += __shfl_xor(ss, 2);
      ss += __shfl_xor(ss, 4); ss += __shfl_xor(ss, 8);
      const float rn = rsqrtf(ss * (1.f / 64.f) + 1e-6f);
      float y[4] = {wv.x * xv.x * rn, wv.y * xv.y * rn, wv.z * xv.z * rn, wv.w * xv.w * rn};
      float rv[4];
      #pragma unroll
      for (int e = 0; e < 4; ++e) {
        float part = __shfl_xor(y[e], 8);
        rv[e] = ((l15 < 8) ? (y[e] * cc[e] - part * sn[e])
                           : (y[e] * cc[e] + part * sn[e])) * 0.18033688f;
      }
      u32x2 w2;
      w2.x = pack2(rv[0], rv[1]);
      w2.y = pack2(rv[2], rv[3]);
      *(u32x2*)&Ks[TILE_U32 + (qrow0 + row) * 32 + 2 * l15] = w2;
    }
  }
  __syncthreads();                       // tile0 K/V loads drained + Q rows visible

  bf16x8 qf[2];
  #pragma unroll
  for (int ks = 0; ks < 2; ++ks)
    qf[ks] = *(const bf16x8*)&Ks[TILE_U32 + (qrow0 + l15) * 32 + 16 * ks + 4 * g];
  __syncthreads();                       // all qf reads done before K buf1 is overwritten

  f32x4 acc_o[4];
  #pragma unroll
  for (int mt = 0; mt < 4; ++mt) acc_o[mt] = (f32x4)(0.f);
  f32x4 acc_l = (f32x4)(0.f);            // l by MFMA: P x ones -> row q, replicated cols

  u32x4 onesw;
  onesw.x = 0x3F803F80u; onesw.y = 0x3F803F80u; onesw.z = 0x3F803F80u; onesw.w = 0x3F803F80u;
  const bf16x8 vones = __builtin_bit_cast(bf16x8, onesw);

  const int q_abs = qb + qrow0 + l15;

  for (int i2 = 0; i2 < nt; ++i2) {
    const int buf = i2 & 1;
    // ---- step 1: issue K(i2+1) prefetch into K buf^1 (8 chunks, 2 per wave) ----
    int tn = -1;
    if (i2 + 1 < nt) {
      tn = (qt <= 18 || i2 + 1 < 2) ? (i2 + 1) : (i2 + 1 + shift);
      const u32* kt = kb + (size_t)tn * TILE_U32;
      u32* kd = &Ks[(buf ^ 1) * TILE_U32];
      #pragma unroll
      for (int j = 0; j < 2; ++j) {
        int ci = (wid << 1) | j;
        gload16(kt + ci * 256 + lane * 4, kd + ci * 256);
      }
    }
    const int k0 = ((qt <= 18 || i2 < 2) ? i2 : i2 + shift) << 6;

    // ---- S^T - 20 = K·Q^T + C(-20) ----
    f32x4 accs[4];
    #pragma unroll
    for (int mt = 0; mt < 4; ++mt) accs[mt] = (f32x4)(SM_BIAS);
    #pragma unroll
    for (int ks = 0; ks < 2; ++ks) {
      #pragma unroll
      for (int mt = 0; mt < 4; ++mt) {
        bf16x8 kf = *(const bf16x8*)&Ks[buf * TILE_U32 + (16 * mt + l15) * 32 + (((4 * ks + g) ^ (l15 & 7)) << 2)];
        accs[mt] = __builtin_amdgcn_mfma_f32_16x16x32_bf16(kf, qf[ks], accs[mt], 0, 0, 0);
      }
    }

    // ---- mask boundary tiles, then P = exp2(S - 20) ----
    const bool do_mask = (i2 == nt - 1) || (qt >= 18 && i2 == 2);
    if (do_mask) {
      #pragma unroll
      for (int mt = 0; mt < 4; ++mt)
        #pragma unroll
        for (int rg = 0; rg < 4; ++rg) {
          int key = k0 + 16 * mt + 4 * g + rg;
          bool ok = (key <= q_abs) && ((key >= q_abs - (WINDOW - 1)) || (key < N_META));
          accs[mt][rg] = ok ? accs[mt][rg] : -INFINITY;
        }
    }
    #pragma unroll
    for (int mt = 0; mt < 4; ++mt)
      #pragma unroll
      for (int rg = 0; rg < 4; ++rg)
        accs[mt][rg] = fexp2(accs[mt][rg]);      // exp2(-inf) = 0 for masked

    // ---- mid-barrier: drains V(i2) writes (issued end of prev tile) + K(i2+1) ----
    __syncthreads();

    // ---- O += P·V, l += P·1 (V^T single buffer) ----
    #pragma unroll
    for (int ks2 = 0; ks2 < 2; ++ks2) {
      const int m0 = 2 * ks2, m1 = 2 * ks2 + 1;
      u32x4 aw;
      aw.x = pack2(accs[m0][0], accs[m0][1]);
      aw.y = pack2(accs[m0][2], accs[m0][3]);
      aw.z = pack2(accs[m1][0], accs[m1][1]);
      aw.w = pack2(accs[m1][2], accs[m1][3]);
      bf16x8 af = __builtin_bit_cast(bf16x8, aw);
      acc_l = __builtin_amdgcn_mfma_f32_16x16x32_bf16(af, vones, acc_l, 0, 0, 0);
      #pragma unroll
      for (int mt2 = 0; mt2 < 4; ++mt2) {
        bf16x8 vf = *(const bf16x8*)&Vt[(16 * mt2 + l15) * 32 + (((4 * ks2 + g) ^ (l15 & 7)) << 2)];
        acc_o[mt2] = __builtin_amdgcn_mfma_f32_16x16x32_bf16(af, vf, acc_o[mt2], 0, 0, 0);
      }
    }

    __syncthreads();     // end-barrier: all waves done reading V(i2) and K buf

    // ---- step 5: issue V(i2+1) into the single V buffer (overwrite now safe) ----
    if (i2 + 1 < nt) {
      const u32* vt = vb + (size_t)tn * TILE_U32;
      #pragma unroll
      for (int j = 0; j < 2; ++j) {
        int ci = (wid << 1) | j;
        gload16(vt + ci * 256 + lane * 4, &Vt[ci * 256]);
      }
    }
  }

  // ---- epilogue: l4[rg] = acc_l[rg] directly (row q'=4g+rg, replicated over cols) ----
  #pragma unroll
  for (int mt2 = 0; mt2 < 4; ++mt2)
    #pragma unroll
    for (int rg = 0; rg < 4; ++rg) {
      int t = qb + qrow0 + 4 * g + rg;
      out[((size_t)(b * T_ + t)) * (N_HEADS * HEAD_DIM) + h * HEAD_DIM + 16 * mt2 + l15] =
          acc_o[mt2][rg] / acc_l[rg];
    }
}

extern "C" void kernel_launch(void* const* d_in, const int* in_sizes, int n_in,
                              void* d_out, int out_size, void* d_ws, size_t ws_size,
                              hipStream_t stream) {
  const float* q   = (const float*)d_in[0];
  const float* k   = (const float*)d_in[1];
  const float* v   = (const float*)d_in[2];
  const float* qw  = (const float*)d_in[3];
  const float* kw  = (const float*)d_in[4];
  const int*   pos = (const int*)d_in[5];

  u32* kp = (u32*)d_ws;                                    // 2.62 MB
  u32* vp = kp + (size_t)B_ * N_KV * NTILES * TILE_U32;    // 2.62 MB
  float* outp = (float*)d_out;

  // merged prep: 320 V-tile blocks + 5120 K-row blocks in one launch
  prep_kernel<<<B_ * N_KV * NTILES + 5120, 256, 0, stream>>>(k, kw, v, pos, kp, vp);
  attn_kernel<<<1600, 256, 0, stream>>>(q, qw, pos, kp, vp, outp);
}

// Round 22
// 55.399 us; speedup vs baseline: 1.5335x; 1.0206x over previous
//
#include <hip/hip_runtime.h>
#include <cmath>

typedef float  f32x4  __attribute__((ext_vector_type(4)));
typedef __bf16 bf16x8 __attribute__((ext_vector_type(8)));
typedef unsigned int u32x4 __attribute__((ext_vector_type(4)));
typedef unsigned int u32x2 __attribute__((ext_vector_type(2)));
typedef unsigned int   u32;
typedef unsigned short u16;

#define HEAD_DIM 64
#define N_HEADS  25
#define N_KV     5
#define WINDOW   1024
#define N_META   128
#define B_       2
#define T_       2048
#define QB       64
#define NTILES   (T_ / 64)
#define TILE_U32 2048               // 64 rows x 32 u32 (8 KB)
// Constant softmax bias: S*0.125*log2e <= (8*1.5)^2*0.125*1.443 ~= 26 (RMSNorm-guaranteed,
// w in [0.5,1.5]). exp2(S-20) <= 64; l <= 6.6e4; min ~= 2^-46 (normal). Scale cancels in O/l.
#define SM_BIAS  (-20.0f)

static __device__ __forceinline__ u16 bf16_bits(float f) {
  __bf16 h = (__bf16)f;
  return __builtin_bit_cast(u16, h);
}
static __device__ __forceinline__ u32 pack2(float lo, float hi) {
  return ((u32)bf16_bits(hi) << 16) | bf16_bits(lo);
}
static __device__ __forceinline__ float fexp2(float x) {
  return __builtin_amdgcn_exp2f(x);    // bare v_exp_f32; exp2(-inf)=0
}
static __device__ __forceinline__ void gload16(const u32* g, u32* l) {
  __builtin_amdgcn_global_load_lds((const __attribute__((address_space(1))) u32*)g,
                                   (__attribute__((address_space(3))) u32*)l, 16, 0, 0);
}

// ---------------- Kernel 1 (merged prep): V-tiles (blk<320) + K-rows (blk>=320) --------
// K ws: [b][kvh][tile][key(64)][seg_phys(8) x 4 u32]; seg_phys = seg_log ^ (key&7)
// V ws: [b][kvh][tile][d(64)][32 u32]; col c=16a+8b+2g+e at seg (4a+g)^(d&7), slot 2b+e
__global__ __launch_bounds__(256) void prep_kernel(
    const float* __restrict__ k_in, const float* __restrict__ k_w,
    const float* __restrict__ v_in, const int* __restrict__ pos_ids,
    u32* __restrict__ k_ws, u32* __restrict__ v_ws)
{
  const int blk = blockIdx.x;
  const int tid = threadIdx.x;

  if (blk < B_ * N_KV * NTILES) {
    // ---------------- V transpose tile ----------------
    int tile = blk & (NTILES - 1);
    int bk   = blk >> 5;
    int kvh  = bk % N_KV, b = bk / N_KV;
    int t0   = tile * 64;

    __shared__ u16 Tl[64][72];           // [d][key]

    #pragma unroll
    for (int it = 0; it < 4; ++it) {
      int idx = it * 256 + tid;
      int kl = idx >> 4, dq = idx & 15;
      const float4 f = *(const float4*)&v_in[((size_t)(b * T_ + t0 + kl)) * (N_KV * HEAD_DIM) + kvh * HEAD_DIM + dq * 4];
      Tl[dq * 4 + 0][kl] = bf16_bits(f.x);
      Tl[dq * 4 + 1][kl] = bf16_bits(f.y);
      Tl[dq * 4 + 2][kl] = bf16_bits(f.z);
      Tl[dq * 4 + 3][kl] = bf16_bits(f.w);
    }
    __syncthreads();

    u32* outb = v_ws + (size_t)blk * TILE_U32;
    #pragma unroll
    for (int it = 0; it < 8; ++it) {
      int o = it * 256 + tid;
      int d = o >> 5, c = o & 31;
      u32 w = ((u32)Tl[d][2 * c + 1] << 16) | Tl[d][2 * c];
      int a = c >> 4, bs = (c >> 3) & 1, gp = (c >> 1) & 3, e = c & 1;
      int sp = (4 * a + gp) ^ (d & 7);
      outb[d * 32 + sp * 4 + 2 * bs + e] = w;
    }
    return;
  }

  // ---------------- K RMSNorm + RoPE rows ----------------
  int gw   = (((blk - B_ * N_KV * NTILES) * 256 + tid) >> 6);
  int lane = tid & 63;
  if (gw >= B_ * T_ * N_KV) return;
  int kvh = gw % N_KV;
  int bt  = gw / N_KV;

  float x = k_in[(size_t)bt * (N_KV * HEAD_DIM) + kvh * HEAD_DIM + lane];
  float ss = x * x;
  #pragma unroll
  for (int off = 32; off; off >>= 1) ss += __shfl_xor(ss, off);
  float y = k_w[lane] * x * rsqrtf(ss * (1.f / 64.f) + 1e-6f);

  int   pos = pos_ids[bt];
  float ang = (float)pos * powf(10000.f, -(float)(lane & 31) * (1.f / 32.f));
  float c, s;
  sincosf(ang, &s, &c);              // sincosf(x, sin*, cos*)
  float part = __shfl_xor(y, 32);
  float r = (lane < 32) ? (y * c - part * s) : (y * c + part * s);

  u16 mybits = bf16_bits(r);
  u32 pb = (u32)(u16)__shfl_xor((int)mybits, 1);
  u32 w  = (pb << 16) | mybits;
  int b = bt / T_, t = bt % T_;
  if (!(lane & 1)) {
    int c32 = lane >> 1;
    int kl = t & 63, tile = t >> 6;
    int sp = (c32 >> 2) ^ (kl & 7);
    k_ws[(((size_t)(b * N_KV + kvh) * NTILES + tile)) * TILE_U32 + kl * 32 + sp * 4 + (c32 & 3)] = w;
  }
}

// ---------------- Kernel 2: fused MFMA flash attention (16KB LDS: K+V single-buffered) -
// Issue points exploit barrier vmcnt-drain: K(i+1) issued after mid-barrier (all QK^T
// reads of K(i) done), drained by end-barrier under PV. V(i+1) issued after end-barrier,
// drained by next mid-barrier under QK^T+softmax. 16KB -> 8 blocks/CU (32-wave cap).
__global__ __launch_bounds__(256, 4) void attn_kernel(
    const float* __restrict__ q_in, const float* __restrict__ q_w,
    const int* __restrict__ pos_ids,
    const u32* __restrict__ kws, const u32* __restrict__ vws,
    float* __restrict__ out)
{
  // XCD-affinity + LPT decode (r14; FETCH 44.8->16.5MB proven).
  const int i  = blockIdx.x;
  const int x  = i & 7, k = i >> 3;
  const int gA = (5 * x) >> 2;
  const int a0 = 200 * x - 160 * gA;
  const int nB = 40 + a0;
  int grp, j_;
  if (k < nB) { grp = gA + 1; j_ = k; }
  else        { grp = gA;     j_ = a0 + (k - nB); }
  const int qt  = 31 - j_ / 5;
  const int hh  = j_ % 5;
  const int b   = grp / 5;
  const int kvh = grp % 5;
  const int h   = kvh * 5 + hh;
  const int qb  = qt * QB;
  const int tid = threadIdx.x, wid = tid >> 6, lane = tid & 63;
  const int l15 = lane & 15, g = lane >> 4;
  const int qrow0 = wid * 16;

  __shared__ u32 Ks[TILE_U32];           // K tile, single-buffered
  __shared__ u32 Vt[TILE_U32];           // V^T tile, single-buffered (Q staging pre-loop)

  const int nt    = (qt <= 18) ? (qt + 1) : 19;
  const int shift = qt - 18;

  const size_t kvbase = ((size_t)(b * N_KV + kvh)) * NTILES * TILE_U32;
  const u32* kb = kws + kvbase;
  const u32* vb = vws + kvbase;

  // ---- prologue: issue K(0)->Ks only (Vt hosts Q staging first) ----
  #pragma unroll
  for (int j = 0; j < 2; ++j) {
    int ci = (wid << 1) | j;             // 8 chunks, 2 per wave
    gload16(kb + ci * 256 + lane * 4, &Ks[ci * 256]);
  }

  // ---- Q staging into Vt, 4-rows-parallel: lane (g,l15) row 4it+g, d=4*l15..+3 ----
  {
    const int   jbase = (4 * l15) & 31;
    const float r32   = 0.74989420933f;            // 10000^(-1/32)
    float fr[4];
    fr[0] = powf(10000.f, -(float)jbase * (1.f / 32.f));
    fr[1] = fr[0] * r32; fr[2] = fr[1] * r32; fr[3] = fr[2] * r32;

    const int t0g = b * T_ + qb + qrow0;
    int pos_prev = pos_ids[t0g + g];
    float cc[4], sn[4], c4[4], s4[4];
    #pragma unroll
    for (int e = 0; e < 4; ++e) {
      sincosf((float)pos_prev * fr[e], &sn[e], &cc[e]);   // sincosf(x, sin*, cos*)
      sincosf(4.f * fr[e], &s4[e], &c4[e]);
    }
    const float4 wv = *(const float4*)&q_w[4 * l15];
    #pragma unroll
    for (int it = 0; it < 4; ++it) {
      const int row = 4 * it + g;
      if (it) {
        int pos = pos_ids[t0g + row];
        if (__all(pos == pos_prev + 4)) {
          #pragma unroll
          for (int e = 0; e < 4; ++e) {
            float c2 = cc[e] * c4[e] - sn[e] * s4[e];
            sn[e] = sn[e] * c4[e] + cc[e] * s4[e];
            cc[e] = c2;
          }
        } else {
          #pragma unroll
          for (int e = 0; e < 4; ++e) sincosf((float)pos * fr[e], &sn[e], &cc[e]);
        }
        pos_prev = pos;
      }
      const float4 xv = *(const float4*)&q_in[((size_t)(t0g + row)) * (N_HEADS * HEAD_DIM) + h * HEAD_DIM + 4 * l15];
      float ss = xv.x * xv.x + xv.y * xv.y + xv.z * xv.z + xv.w * xv.w;
      ss += __shfl_xor(ss, 1); ss += __shfl_xor(ss, 2);
      ss += __shfl_xor(ss, 4); ss += __shfl_xor(ss, 8);
      const float rn = rsqrtf(ss * (1.f / 64.f) + 1e-6f);
      float y[4] = {wv.x * xv.x * rn, wv.y * xv.y * rn, wv.z * xv.z * rn, wv.w * xv.w * rn};
      float rv[4];
      #pragma unroll
      for (int e = 0; e < 4; ++e) {
        float part = __shfl_xor(y[e], 8);
        rv[e] = ((l15 < 8) ? (y[e] * cc[e] - part * sn[e])
                           : (y[e] * cc[e] + part * sn[e])) * 0.18033688f;
      }
      u32x2 w2;
      w2.x = pack2(rv[0], rv[1]);
      w2.y = pack2(rv[2], rv[3]);
      *(u32x2*)&Vt[(qrow0 + row) * 32 + 2 * l15] = w2;
    }
  }
  __syncthreads();                       // K(0) drained + Q rows visible in Vt

  bf16x8 qf[2];
  #pragma unroll
  for (int ks = 0; ks < 2; ++ks)
    qf[ks] = *(const bf16x8*)&Vt[(qrow0 + l15) * 32 + 16 * ks + 4 * g];
  __syncthreads();                       // all qf reads done -> Vt free for V(0)

  // ---- issue V(0) into Vt (drained by tile-0 mid-barrier under QK^T+softmax) ----
  #pragma unroll
  for (int j = 0; j < 2; ++j) {
    int ci = (wid << 1) | j;
    gload16(vb + ci * 256 + lane * 4, &Vt[ci * 256]);
  }

  f32x4 acc_o[4];
  #pragma unroll
  for (int mt = 0; mt < 4; ++mt) acc_o[mt] = (f32x4)(0.f);
  f32x4 acc_l = (f32x4)(0.f);            // l by MFMA: P x ones -> row q, replicated cols

  u32x4 onesw;
  onesw.x = 0x3F803F80u; onesw.y = 0x3F803F80u; onesw.z = 0x3F803F80u; onesw.w = 0x3F803F80u;
  const bf16x8 vones = __builtin_bit_cast(bf16x8, onesw);

  const int q_abs = qb + qrow0 + l15;

  for (int i2 = 0; i2 < nt; ++i2) {
    const int k0 = ((qt <= 18 || i2 < 2) ? i2 : i2 + shift) << 6;
    int tn = -1;
    if (i2 + 1 < nt) tn = (qt <= 18 || i2 + 1 < 2) ? (i2 + 1) : (i2 + 1 + shift);

    // ---- S^T - 20 = K·Q^T + C(-20)  (reads Ks = K(i2)) ----
    f32x4 accs[4];
    #pragma unroll
    for (int mt = 0; mt < 4; ++mt) accs[mt] = (f32x4)(SM_BIAS);
    #pragma unroll
    for (int ks = 0; ks < 2; ++ks) {
      #pragma unroll
      for (int mt = 0; mt < 4; ++mt) {
        bf16x8 kf = *(const bf16x8*)&Ks[(16 * mt + l15) * 32 + (((4 * ks + g) ^ (l15 & 7)) << 2)];
        accs[mt] = __builtin_amdgcn_mfma_f32_16x16x32_bf16(kf, qf[ks], accs[mt], 0, 0, 0);
      }
    }

    // ---- mask boundary tiles, then P = exp2(S - 20) ----
    const bool do_mask = (i2 == nt - 1) || (qt >= 18 && i2 == 2);
    if (do_mask) {
      #pragma unroll
      for (int mt = 0; mt < 4; ++mt)
        #pragma unroll
        for (int rg = 0; rg < 4; ++rg) {
          int key = k0 + 16 * mt + 4 * g + rg;
          bool ok = (key <= q_abs) && ((key >= q_abs - (WINDOW - 1)) || (key < N_META));
          accs[mt][rg] = ok ? accs[mt][rg] : -INFINITY;
        }
    }
    #pragma unroll
    for (int mt = 0; mt < 4; ++mt)
      #pragma unroll
      for (int rg = 0; rg < 4; ++rg)
        accs[mt][rg] = fexp2(accs[mt][rg]);      // exp2(-inf) = 0 for masked

    // ---- mid-barrier: drains V(i2) (issued ~1 phase earlier) ----
    __syncthreads();

    // ---- issue K(i2+1) into Ks (all QK^T reads of K(i2) done across waves) ----
    if (tn >= 0) {
      const u32* kt = kb + (size_t)tn * TILE_U32;
      #pragma unroll
      for (int j = 0; j < 2; ++j) {
        int ci = (wid << 1) | j;
        gload16(kt + ci * 256 + lane * 4, &Ks[ci * 256]);
      }
    }

    // ---- O += P·V, l += P·1 (reads Vt = V(i2)) ----
    #pragma unroll
    for (int ks2 = 0; ks2 < 2; ++ks2) {
      const int m0 = 2 * ks2, m1 = 2 * ks2 + 1;
      u32x4 aw;
      aw.x = pack2(accs[m0][0], accs[m0][1]);
      aw.y = pack2(accs[m0][2], accs[m0][3]);
      aw.z = pack2(accs[m1][0], accs[m1][1]);
      aw.w = pack2(accs[m1][2], accs[m1][3]);
      bf16x8 af = __builtin_bit_cast(bf16x8, aw);
      acc_l = __builtin_amdgcn_mfma_f32_16x16x32_bf16(af, vones, acc_l, 0, 0, 0);
      #pragma unroll
      for (int mt2 = 0; mt2 < 4; ++mt2) {
        bf16x8 vf = *(const bf16x8*)&Vt[(16 * mt2 + l15) * 32 + (((4 * ks2 + g) ^ (l15 & 7)) << 2)];
        acc_o[mt2] = __builtin_amdgcn_mfma_f32_16x16x32_bf16(af, vf, acc_o[mt2], 0, 0, 0);
      }
    }

    __syncthreads();     // end-barrier: drains K(i2+1); all V(i2) reads done

    // ---- issue V(i2+1) into Vt (drained by next mid-barrier) ----
    if (tn >= 0) {
      const u32* vt = vb + (size_t)tn * TILE_U32;
      #pragma unroll
      for (int j = 0; j < 2; ++j) {
        int ci = (wid << 1) | j;
        gload16(vt + ci * 256 + lane * 4, &Vt[ci * 256]);
      }
    }
  }

  // ---- epilogue: l4[rg] = acc_l[rg] directly (row q'=4g+rg, replicated over cols) ----
  #pragma unroll
  for (int mt2 = 0; mt2 < 4; ++mt2)
    #pragma unroll
    for (int rg = 0; rg < 4; ++rg) {
      int t = qb + qrow0 + 4 * g + rg;
      out[((size_t)(b * T_ + t)) * (N_HEADS * HEAD_DIM) + h * HEAD_DIM + 16 * mt2 + l15] =
          acc_o[mt2][rg] / acc_l[rg];
    }
}

extern "C" void kernel_launch(void* const* d_in, const int* in_sizes, int n_in,
                              void* d_out, int out_size, void* d_ws, size_t ws_size,
                              hipStream_t stream) {
  const float* q   = (const float*)d_in[0];
  const float* k   = (const float*)d_in[1];
  const float* v   = (const float*)d_in[2];
  const float* qw  = (const float*)d_in[3];
  const float* kw  = (const float*)d_in[4];
  const int*   pos = (const int*)d_in[5];

  u32* kp = (u32*)d_ws;                                    // 2.62 MB
  u32* vp = kp + (size_t)B_ * N_KV * NTILES * TILE_U32;    // 2.62 MB
  float* outp = (float*)d_out;

  // merged prep: 320 V-tile blocks + 5120 K-row blocks in one launch
  prep_kernel<<<B_ * N_KV * NTILES + 5120, 256, 0, stream>>>(k, kw, v, pos, kp, vp);
  attn_kernel<<<1600, 256, 0, stream>>>(q, qw, pos, kp, vp, outp);
}

// Round 23
// 52.575 us; speedup vs baseline: 1.6158x; 1.0537x over previous
//
#include <hip/hip_runtime.h>
#include <cmath>

typedef float  f32x4  __attribute__((ext_vector_type(4)));
typedef __bf16 bf16x8 __attribute__((ext_vector_type(8)));
typedef unsigned int u32x4 __attribute__((ext_vector_type(4)));
typedef unsigned int u32x2 __attribute__((ext_vector_type(2)));
typedef unsigned int   u32;
typedef unsigned short u16;

#define HEAD_DIM 64
#define N_HEADS  25
#define N_KV     5
#define WINDOW   1024
#define N_META   128
#define B_       2
#define T_       2048
#define QB       64
#define NTILES   (T_ / 64)
#define TILE_U32 2048               // 64 rows x 32 u32 (8 KB)
// Constant softmax bias: S*0.125*log2e <= (8*1.5)^2*0.125*1.443 ~= 26 (RMSNorm-guaranteed,
// w in [0.5,1.5]). exp2(S-20) <= 64; l <= 6.6e4; min ~= 2^-46 (normal). Scale cancels in O/l.
#define SM_BIAS  (-20.0f)

static __device__ __forceinline__ u16 bf16_bits(float f) {
  __bf16 h = (__bf16)f;
  return __builtin_bit_cast(u16, h);
}
static __device__ __forceinline__ u32 pack2(float lo, float hi) {
  return ((u32)bf16_bits(hi) << 16) | bf16_bits(lo);
}
static __device__ __forceinline__ float fexp2(float x) {
  return __builtin_amdgcn_exp2f(x);    // bare v_exp_f32; exp2(-inf)=0
}
static __device__ __forceinline__ void gload16(const u32* g, u32* l) {
  __builtin_amdgcn_global_load_lds((const __attribute__((address_space(1))) u32*)g,
                                   (__attribute__((address_space(3))) u32*)l, 16, 0, 0);
}

// ---------------- Kernel 1 (merged prep): V-tiles (blk<320) + K 16-row waves (blk>=320) -
// K ws: [b][kvh][tile][key(64)][seg_phys(8) x 4 u32]; seg_phys = seg_log ^ (key&7)
// V ws: [b][kvh][tile][d(64)][32 u32]; col c=16a+8b+2g+e at seg (4a+g)^(d&7), slot 2b+e
// K-prep now r16-style: wave owns 16 consecutive rows of one (b,kvh); lane (g,l15) does
// row 4*it+g, d=4*l15..+3; rotation recurrence (angle 4f per iter, sincosf fallback).
__global__ __launch_bounds__(256) void prep_kernel(
    const float* __restrict__ k_in, const float* __restrict__ k_w,
    const float* __restrict__ v_in, const int* __restrict__ pos_ids,
    u32* __restrict__ k_ws, u32* __restrict__ v_ws)
{
  const int blk = blockIdx.x;
  const int tid = threadIdx.x;

  if (blk < B_ * N_KV * NTILES) {
    // ---------------- V transpose tile ----------------
    int tile = blk & (NTILES - 1);
    int bk   = blk >> 5;
    int kvh  = bk % N_KV, b = bk / N_KV;
    int t0   = tile * 64;

    __shared__ u16 Tl[64][72];           // [d][key]

    #pragma unroll
    for (int it = 0; it < 4; ++it) {
      int idx = it * 256 + tid;
      int kl = idx >> 4, dq = idx & 15;
      const float4 f = *(const float4*)&v_in[((size_t)(b * T_ + t0 + kl)) * (N_KV * HEAD_DIM) + kvh * HEAD_DIM + dq * 4];
      Tl[dq * 4 + 0][kl] = bf16_bits(f.x);
      Tl[dq * 4 + 1][kl] = bf16_bits(f.y);
      Tl[dq * 4 + 2][kl] = bf16_bits(f.z);
      Tl[dq * 4 + 3][kl] = bf16_bits(f.w);
    }
    __syncthreads();

    u32* outb = v_ws + (size_t)blk * TILE_U32;
    #pragma unroll
    for (int it = 0; it < 8; ++it) {
      int o = it * 256 + tid;
      int d = o >> 5, c = o & 31;
      u32 w = ((u32)Tl[d][2 * c + 1] << 16) | Tl[d][2 * c];
      int a = c >> 4, bs = (c >> 3) & 1, gp = (c >> 1) & 3, e = c & 1;
      int sp = (4 * a + gp) ^ (d & 7);
      outb[d * 32 + sp * 4 + 2 * bs + e] = w;
    }
    return;
  }

  // ---------------- K RMSNorm + RoPE, 16 rows per wave ----------------
  const int lane = tid & 63, wid = tid >> 6;
  const int l15 = lane & 15, g = lane >> 4;
  const int gw   = (blk - B_ * N_KV * NTILES) * 4 + wid;   // 0..1279
  const int bkvh = gw >> 7;                                // 0..9 = b*5+kvh
  const int sl   = gw & 127;
  const int b    = bkvh / N_KV, kvh = bkvh % N_KV;
  const int t0   = sl * 16;

  const int   jbase = (4 * l15) & 31;
  const float r32   = 0.74989420933f;                      // 10000^(-1/32)
  float fr[4];
  fr[0] = powf(10000.f, -(float)jbase * (1.f / 32.f));
  fr[1] = fr[0] * r32; fr[2] = fr[1] * r32; fr[3] = fr[2] * r32;

  const int t0g = b * T_ + t0;
  int pos_prev = pos_ids[t0g + g];
  float cc[4], sn[4], c4[4], s4[4];
  #pragma unroll
  for (int e = 0; e < 4; ++e) {
    sincosf((float)pos_prev * fr[e], &sn[e], &cc[e]);      // sincosf(x, sin*, cos*)
    sincosf(4.f * fr[e], &s4[e], &c4[e]);
  }
  const float4 wv = *(const float4*)&k_w[4 * l15];
  u32* outb = k_ws + ((size_t)bkvh * NTILES + (t0 >> 6)) * TILE_U32;
  const int klbase = t0 & 63;
  const int sp_c   = l15 >> 1;                             // c32 pair seg base (2*l15)>>2
  const int slot   = (2 * l15) & 3;

  #pragma unroll
  for (int it = 0; it < 4; ++it) {
    const int row = 4 * it + g;
    if (it) {
      int pos = pos_ids[t0g + row];
      if (__all(pos == pos_prev + 4)) {
        #pragma unroll
        for (int e = 0; e < 4; ++e) {
          float c2 = cc[e] * c4[e] - sn[e] * s4[e];
          sn[e] = sn[e] * c4[e] + cc[e] * s4[e];
          cc[e] = c2;
        }
      } else {
        #pragma unroll
        for (int e = 0; e < 4; ++e) sincosf((float)pos * fr[e], &sn[e], &cc[e]);
      }
      pos_prev = pos;
    }
    const float4 xv = *(const float4*)&k_in[((size_t)(t0g + row)) * (N_KV * HEAD_DIM) + kvh * HEAD_DIM + 4 * l15];
    float ss = xv.x * xv.x + xv.y * xv.y + xv.z * xv.z + xv.w * xv.w;
    ss += __shfl_xor(ss, 1); ss += __shfl_xor(ss, 2);
    ss += __shfl_xor(ss, 4); ss += __shfl_xor(ss, 8);
    const float rn = rsqrtf(ss * (1.f / 64.f) + 1e-6f);
    float y[4] = {wv.x * xv.x * rn, wv.y * xv.y * rn, wv.z * xv.z * rn, wv.w * xv.w * rn};
    float rv[4];
    #pragma unroll
    for (int e = 0; e < 4; ++e) {
      float part = __shfl_xor(y[e], 8);
      rv[e] = (l15 < 8) ? (y[e] * cc[e] - part * sn[e])
                        : (y[e] * cc[e] + part * sn[e]);   // NO scale on K
    }
    const int kl = klbase + row;
    const int sp = sp_c ^ (kl & 7);
    u32x2 w2;
    w2.x = pack2(rv[0], rv[1]);
    w2.y = pack2(rv[2], rv[3]);
    *(u32x2*)&outb[kl * 32 + sp * 4 + slot] = w2;
  }
}

// ---------------- Kernel 2: fused MFMA flash attention (r22: 16KB LDS, single-buffered) -
__global__ __launch_bounds__(256, 4) void attn_kernel(
    const float* __restrict__ q_in, const float* __restrict__ q_w,
    const int* __restrict__ pos_ids,
    const u32* __restrict__ kws, const u32* __restrict__ vws,
    float* __restrict__ out)
{
  // XCD-affinity + LPT decode (r14; FETCH 44.8->16.5MB proven).
  const int i  = blockIdx.x;
  const int x  = i & 7, k = i >> 3;
  const int gA = (5 * x) >> 2;
  const int a0 = 200 * x - 160 * gA;
  const int nB = 40 + a0;
  int grp, j_;
  if (k < nB) { grp = gA + 1; j_ = k; }
  else        { grp = gA;     j_ = a0 + (k - nB); }
  const int qt  = 31 - j_ / 5;
  const int hh  = j_ % 5;
  const int b   = grp / 5;
  const int kvh = grp % 5;
  const int h   = kvh * 5 + hh;
  const int qb  = qt * QB;
  const int tid = threadIdx.x, wid = tid >> 6, lane = tid & 63;
  const int l15 = lane & 15, g = lane >> 4;
  const int qrow0 = wid * 16;

  __shared__ u32 Ks[TILE_U32];           // K tile, single-buffered
  __shared__ u32 Vt[TILE_U32];           // V^T tile, single-buffered (Q staging pre-loop)

  const int nt    = (qt <= 18) ? (qt + 1) : 19;
  const int shift = qt - 18;

  const size_t kvbase = ((size_t)(b * N_KV + kvh)) * NTILES * TILE_U32;
  const u32* kb = kws + kvbase;
  const u32* vb = vws + kvbase;

  // ---- prologue: issue K(0)->Ks only (Vt hosts Q staging first) ----
  #pragma unroll
  for (int j = 0; j < 2; ++j) {
    int ci = (wid << 1) | j;             // 8 chunks, 2 per wave
    gload16(kb + ci * 256 + lane * 4, &Ks[ci * 256]);
  }

  // ---- Q staging into Vt, 4-rows-parallel: lane (g,l15) row 4it+g, d=4*l15..+3 ----
  {
    const int   jbase = (4 * l15) & 31;
    const float r32   = 0.74989420933f;            // 10000^(-1/32)
    float fr[4];
    fr[0] = powf(10000.f, -(float)jbase * (1.f / 32.f));
    fr[1] = fr[0] * r32; fr[2] = fr[1] * r32; fr[3] = fr[2] * r32;

    const int t0g = b * T_ + qb + qrow0;
    int pos_prev = pos_ids[t0g + g];
    float cc[4], sn[4], c4[4], s4[4];
    #pragma unroll
    for (int e = 0; e < 4; ++e) {
      sincosf((float)pos_prev * fr[e], &sn[e], &cc[e]);   // sincosf(x, sin*, cos*)
      sincosf(4.f * fr[e], &s4[e], &c4[e]);
    }
    const float4 wv = *(const float4*)&q_w[4 * l15];
    #pragma unroll
    for (int it = 0; it < 4; ++it) {
      const int row = 4 * it + g;
      if (it) {
        int pos = pos_ids[t0g + row];
        if (__all(pos == pos_prev + 4)) {
          #pragma unroll
          for (int e = 0; e < 4; ++e) {
            float c2 = cc[e] * c4[e] - sn[e] * s4[e];
            sn[e] = sn[e] * c4[e] + cc[e] * s4[e];
            cc[e] = c2;
          }
        } else {
          #pragma unroll
          for (int e = 0; e < 4; ++e) sincosf((float)pos * fr[e], &sn[e], &cc[e]);
        }
        pos_prev = pos;
      }
      const float4 xv = *(const float4*)&q_in[((size_t)(t0g + row)) * (N_HEADS * HEAD_DIM) + h * HEAD_DIM + 4 * l15];
      float ss = xv.x * xv.x + xv.y * xv.y + xv.z * xv.z + xv.w * xv.w;
      ss += __shfl_xor(ss, 1); ss += __shfl_xor(ss, 2);
      ss += __shfl_xor(ss, 4); ss += __shfl_xor(ss, 8);
      const float rn = rsqrtf(ss * (1.f / 64.f) + 1e-6f);
      float y[4] = {wv.x * xv.x * rn, wv.y * xv.y * rn, wv.z * xv.z * rn, wv.w * xv.w * rn};
      float rv[4];
      #pragma unroll
      for (int e = 0; e < 4; ++e) {
        float part = __shfl_xor(y[e], 8);
        rv[e] = ((l15 < 8) ? (y[e] * cc[e] - part * sn[e])
                           : (y[e] * cc[e] + part * sn[e])) * 0.18033688f;
      }
      u32x2 w2;
      w2.x = pack2(rv[0], rv[1]);
      w2.y = pack2(rv[2], rv[3]);
      *(u32x2*)&Vt[(qrow0 + row) * 32 + 2 * l15] = w2;
    }
  }
  __syncthreads();                       // K(0) drained + Q rows visible in Vt

  bf16x8 qf[2];
  #pragma unroll
  for (int ks = 0; ks < 2; ++ks)
    qf[ks] = *(const bf16x8*)&Vt[(qrow0 + l15) * 32 + 16 * ks + 4 * g];
  __syncthreads();                       // all qf reads done -> Vt free for V(0)

  // ---- issue V(0) into Vt (drained by tile-0 mid-barrier under QK^T+softmax) ----
  #pragma unroll
  for (int j = 0; j < 2; ++j) {
    int ci = (wid << 1) | j;
    gload16(vb + ci * 256 + lane * 4, &Vt[ci * 256]);
  }

  f32x4 acc_o[4];
  #pragma unroll
  for (int mt = 0; mt < 4; ++mt) acc_o[mt] = (f32x4)(0.f);
  f32x4 acc_l = (f32x4)(0.f);            // l by MFMA: P x ones -> row q, replicated cols

  u32x4 onesw;
  onesw.x = 0x3F803F80u; onesw.y = 0x3F803F80u; onesw.z = 0x3F803F80u; onesw.w = 0x3F803F80u;
  const bf16x8 vones = __builtin_bit_cast(bf16x8, onesw);

  const int q_abs = qb + qrow0 + l15;

  for (int i2 = 0; i2 < nt; ++i2) {
    const int k0 = ((qt <= 18 || i2 < 2) ? i2 : i2 + shift) << 6;
    int tn = -1;
    if (i2 + 1 < nt) tn = (qt <= 18 || i2 + 1 < 2) ? (i2 + 1) : (i2 + 1 + shift);

    // ---- S^T - 20 = K·Q^T + C(-20)  (reads Ks = K(i2)) ----
    f32x4 accs[4];
    #pragma unroll
    for (int mt = 0; mt < 4; ++mt) accs[mt] = (f32x4)(SM_BIAS);
    #pragma unroll
    for (int ks = 0; ks < 2; ++ks) {
      #pragma unroll
      for (int mt = 0; mt < 4; ++mt) {
        bf16x8 kf = *(const bf16x8*)&Ks[(16 * mt + l15) * 32 + (((4 * ks + g) ^ (l15 & 7)) << 2)];
        accs[mt] = __builtin_amdgcn_mfma_f32_16x16x32_bf16(kf, qf[ks], accs[mt], 0, 0, 0);
      }
    }

    // ---- mask boundary tiles, then P = exp2(S - 20) ----
    const bool do_mask = (i2 == nt - 1) || (qt >= 18 && i2 == 2);
    if (do_mask) {
      #pragma unroll
      for (int mt = 0; mt < 4; ++mt)
        #pragma unroll
        for (int rg = 0; rg < 4; ++rg) {
          int key = k0 + 16 * mt + 4 * g + rg;
          bool ok = (key <= q_abs) && ((key >= q_abs - (WINDOW - 1)) || (key < N_META));
          accs[mt][rg] = ok ? accs[mt][rg] : -INFINITY;
        }
    }
    #pragma unroll
    for (int mt = 0; mt < 4; ++mt)
      #pragma unroll
      for (int rg = 0; rg < 4; ++rg)
        accs[mt][rg] = fexp2(accs[mt][rg]);      // exp2(-inf) = 0 for masked

    // ---- mid-barrier: drains V(i2) (issued ~1 phase earlier) ----
    __syncthreads();

    // ---- issue K(i2+1) into Ks (all QK^T reads of K(i2) done across waves) ----
    if (tn >= 0) {
      const u32* kt = kb + (size_t)tn * TILE_U32;
      #pragma unroll
      for (int j = 0; j < 2; ++j) {
        int ci = (wid << 1) | j;
        gload16(kt + ci * 256 + lane * 4, &Ks[ci * 256]);
      }
    }

    // ---- O += P·V, l += P·1 (reads Vt = V(i2)) ----
    #pragma unroll
    for (int ks2 = 0; ks2 < 2; ++ks2) {
      const int m0 = 2 * ks2, m1 = 2 * ks2 + 1;
      u32x4 aw;
      aw.x = pack2(accs[m0][0], accs[m0][1]);
      aw.y = pack2(accs[m0][2], accs[m0][3]);
      aw.z = pack2(accs[m1][0], accs[m1][1]);
      aw.w = pack2(accs[m1][2], accs[m1][3]);
      bf16x8 af = __builtin_bit_cast(bf16x8, aw);
      acc_l = __builtin_amdgcn_mfma_f32_16x16x32_bf16(af, vones, acc_l, 0, 0, 0);
      #pragma unroll
      for (int mt2 = 0; mt2 < 4; ++mt2) {
        bf16x8 vf = *(const bf16x8*)&Vt[(16 * mt2 + l15) * 32 + (((4 * ks2 + g) ^ (l15 & 7)) << 2)];
        acc_o[mt2] = __builtin_amdgcn_mfma_f32_16x16x32_bf16(af, vf, acc_o[mt2], 0, 0, 0);
      }
    }

    __syncthreads();     // end-barrier: drains K(i2+1); all V(i2) reads done

    // ---- issue V(i2+1) into Vt (drained by next mid-barrier) ----
    if (tn >= 0) {
      const u32* vt = vb + (size_t)tn * TILE_U32;
      #pragma unroll
      for (int j = 0; j < 2; ++j) {
        int ci = (wid << 1) | j;
        gload16(vt + ci * 256 + lane * 4, &Vt[ci * 256]);
      }
    }
  }

  // ---- epilogue: l4[rg] = acc_l[rg] directly (row q'=4g+rg, replicated over cols) ----
  #pragma unroll
  for (int mt2 = 0; mt2 < 4; ++mt2)
    #pragma unroll
    for (int rg = 0; rg < 4; ++rg) {
      int t = qb + qrow0 + 4 * g + rg;
      out[((size_t)(b * T_ + t)) * (N_HEADS * HEAD_DIM) + h * HEAD_DIM + 16 * mt2 + l15] =
          acc_o[mt2][rg] / acc_l[rg];
    }
}

extern "C" void kernel_launch(void* const* d_in, const int* in_sizes, int n_in,
                              void* d_out, int out_size, void* d_ws, size_t ws_size,
                              hipStream_t stream) {
  const float* q   = (const float*)d_in[0];
  const float* k   = (const float*)d_in[1];
  const float* v   = (const float*)d_in[2];
  const float* qw  = (const float*)d_in[3];
  const float* kw  = (const float*)d_in[4];
  const int*   pos = (const int*)d_in[5];

  u32* kp = (u32*)d_ws;                                    // 2.62 MB
  u32* vp = kp + (size_t)B_ * N_KV * NTILES * TILE_U32;    // 2.62 MB
  float* outp = (float*)d_out;

  // merged prep: 320 V-tile blocks + 320 K-wave blocks (16 rows/wave) in one launch
  prep_kernel<<<2 * B_ * N_KV * NTILES, 256, 0, stream>>>(k, kw, v, pos, kp, vp);
  attn_kernel<<<1600, 256, 0, stream>>>(q, qw, pos, kp, vp, outp);
}

// Round 24
// 52.289 us; speedup vs baseline: 1.6247x; 1.0055x over previous
//
#include <hip/hip_runtime.h>
#include <cmath>

typedef float  f32x4  __attribute__((ext_vector_type(4)));
typedef __bf16 bf16x8 __attribute__((ext_vector_type(8)));
typedef unsigned int u32x4 __attribute__((ext_vector_type(4)));
typedef unsigned int u32x2 __attribute__((ext_vector_type(2)));
typedef unsigned int   u32;
typedef unsigned short u16;

#define HEAD_DIM 64
#define N_HEADS  25
#define N_KV     5
#define WINDOW   1024
#define N_META   128
#define B_       2
#define T_       2048
#define QB       64
#define NTILES   (T_ / 64)
#define TILE_U32 2048               // 64 rows x 32 u32 (8 KB)
// Constant softmax bias: S*0.125*log2e <= (8*1.5)^2*0.125*1.443 ~= 26 (RMSNorm-guaranteed,
// w in [0.5,1.5]). exp2(S-20) <= 64; l <= 6.6e4; min ~= 2^-46 (normal). Scale cancels in O/l.
#define SM_BIAS  (-20.0f)

static __device__ __forceinline__ u16 bf16_bits(float f) {
  __bf16 h = (__bf16)f;
  return __builtin_bit_cast(u16, h);
}
static __device__ __forceinline__ u32 pack2(float lo, float hi) {
  return ((u32)bf16_bits(hi) << 16) | bf16_bits(lo);
}
static __device__ __forceinline__ float fexp2(float x) {
  return __builtin_amdgcn_exp2f(x);    // bare v_exp_f32; exp2(-inf)=0
}
static __device__ __forceinline__ void gload16(const u32* g, u32* l) {
  __builtin_amdgcn_global_load_lds((const __attribute__((address_space(1))) u32*)g,
                                   (__attribute__((address_space(3))) u32*)l, 16, 0, 0);
}

// ---------------- Kernel 1 (merged prep): V-tiles (blk<320) + K 16-row waves (blk>=320) -
// K ws: [b][kvh][tile][key(64)][seg_phys(8) x 4 u32]; seg_phys = seg_log ^ (key&7)
// V ws: [b][kvh][tile][d(64)][32 u32]; col c=16a+8b+2g+e at seg (4a+g)^(d&7), slot 2b+e
__global__ __launch_bounds__(256) void prep_kernel(
    const float* __restrict__ k_in, const float* __restrict__ k_w,
    const float* __restrict__ v_in, const int* __restrict__ pos_ids,
    u32* __restrict__ k_ws, u32* __restrict__ v_ws)
{
  const int blk = blockIdx.x;
  const int tid = threadIdx.x;

  if (blk < B_ * N_KV * NTILES) {
    // ---------------- V transpose tile ----------------
    int tile = blk & (NTILES - 1);
    int bk   = blk >> 5;
    int kvh  = bk % N_KV, b = bk / N_KV;
    int t0   = tile * 64;

    __shared__ u16 Tl[64][72];           // [d][key]

    #pragma unroll
    for (int it = 0; it < 4; ++it) {
      int idx = it * 256 + tid;
      int kl = idx >> 4, dq = idx & 15;
      const float4 f = *(const float4*)&v_in[((size_t)(b * T_ + t0 + kl)) * (N_KV * HEAD_DIM) + kvh * HEAD_DIM + dq * 4];
      Tl[dq * 4 + 0][kl] = bf16_bits(f.x);
      Tl[dq * 4 + 1][kl] = bf16_bits(f.y);
      Tl[dq * 4 + 2][kl] = bf16_bits(f.z);
      Tl[dq * 4 + 3][kl] = bf16_bits(f.w);
    }
    __syncthreads();

    u32* outb = v_ws + (size_t)blk * TILE_U32;
    #pragma unroll
    for (int it = 0; it < 8; ++it) {
      int o = it * 256 + tid;
      int d = o >> 5, c = o & 31;
      u32 w = ((u32)Tl[d][2 * c + 1] << 16) | Tl[d][2 * c];
      int a = c >> 4, bs = (c >> 3) & 1, gp = (c >> 1) & 3, e = c & 1;
      int sp = (4 * a + gp) ^ (d & 7);
      outb[d * 32 + sp * 4 + 2 * bs + e] = w;
    }
    return;
  }

  // ---------------- K RMSNorm + RoPE, 16 rows per wave ----------------
  const int lane = tid & 63, wid = tid >> 6;
  const int l15 = lane & 15, g = lane >> 4;
  const int gw   = (blk - B_ * N_KV * NTILES) * 4 + wid;   // 0..1279
  const int bkvh = gw >> 7;                                // 0..9 = b*5+kvh
  const int sl   = gw & 127;
  const int b    = bkvh / N_KV, kvh = bkvh % N_KV;
  const int t0   = sl * 16;

  const int   jbase = (4 * l15) & 31;
  const float r32   = 0.74989420933f;                      // 10000^(-1/32)
  float fr[4];
  fr[0] = powf(10000.f, -(float)jbase * (1.f / 32.f));
  fr[1] = fr[0] * r32; fr[2] = fr[1] * r32; fr[3] = fr[2] * r32;

  const int t0g = b * T_ + t0;
  int pos_prev = pos_ids[t0g + g];
  float cc[4], sn[4], c4[4], s4[4];
  #pragma unroll
  for (int e = 0; e < 4; ++e) {
    sincosf((float)pos_prev * fr[e], &sn[e], &cc[e]);      // sincosf(x, sin*, cos*)
    sincosf(4.f * fr[e], &s4[e], &c4[e]);
  }
  const float4 wv = *(const float4*)&k_w[4 * l15];
  u32* outb = k_ws + ((size_t)bkvh * NTILES + (t0 >> 6)) * TILE_U32;
  const int klbase = t0 & 63;
  const int sp_c   = l15 >> 1;
  const int slot   = (2 * l15) & 3;

  #pragma unroll
  for (int it = 0; it < 4; ++it) {
    const int row = 4 * it + g;
    if (it) {
      int pos = pos_ids[t0g + row];
      if (__all(pos == pos_prev + 4)) {
        #pragma unroll
        for (int e = 0; e < 4; ++e) {
          float c2 = cc[e] * c4[e] - sn[e] * s4[e];
          sn[e] = sn[e] * c4[e] + cc[e] * s4[e];
          cc[e] = c2;
        }
      } else {
        #pragma unroll
        for (int e = 0; e < 4; ++e) sincosf((float)pos * fr[e], &sn[e], &cc[e]);
      }
      pos_prev = pos;
    }
    const float4 xv = *(const float4*)&k_in[((size_t)(t0g + row)) * (N_KV * HEAD_DIM) + kvh * HEAD_DIM + 4 * l15];
    float ss = xv.x * xv.x + xv.y * xv.y + xv.z * xv.z + xv.w * xv.w;
    ss += __shfl_xor(ss, 1); ss += __shfl_xor(ss, 2);
    ss += __shfl_xor(ss, 4); ss += __shfl_xor(ss, 8);
    const float rn = rsqrtf(ss * (1.f / 64.f) + 1e-6f);
    float y[4] = {wv.x * xv.x * rn, wv.y * xv.y * rn, wv.z * xv.z * rn, wv.w * xv.w * rn};
    float rv[4];
    #pragma unroll
    for (int e = 0; e < 4; ++e) {
      float part = __shfl_xor(y[e], 8);
      rv[e] = (l15 < 8) ? (y[e] * cc[e] - part * sn[e])
                        : (y[e] * cc[e] + part * sn[e]);   // NO scale on K
    }
    const int kl = klbase + row;
    const int sp = sp_c ^ (kl & 7);
    u32x2 w2;
    w2.x = pack2(rv[0], rv[1]);
    w2.y = pack2(rv[2], rv[3]);
    *(u32x2*)&outb[kl * 32 + sp * 4 + slot] = w2;
  }
}

// ---------------- Kernel 2: fused MFMA flash attention (r23 + snake CU-balancing) ------
__global__ __launch_bounds__(256, 4) void attn_kernel(
    const float* __restrict__ q_in, const float* __restrict__ q_w,
    const int* __restrict__ pos_ids,
    const u32* __restrict__ kws, const u32* __restrict__ vws,
    float* __restrict__ out)
{
  // XCD-affinity decode (r14) + snake CU-balancing (r24):
  // All 1600 blocks are co-resident; wall = max per-CU work. Slot s of an XCD queue
  // lands on CU s%32 (round-robin model). Queue tile-counts are ~descending, so
  // reversing odd 32-slot rows (boustrophedon) equalizes per-CU tile sums.
  // Bijective within each row; preserves per-XCD group affinity (L2 win intact).
  const int i  = blockIdx.x;
  const int x  = i & 7;
  int k = i >> 3;                                  // slot in this XCD's 200-queue
  {
    const int row = k >> 5, col = k & 31;
    const int base = row * 32;
    const int span = (200 - base < 32) ? (200 - base) : 32;
    k = base + ((row & 1) ? (span - 1 - col) : col);
  }
  const int gA = (5 * x) >> 2;
  const int a0 = 200 * x - 160 * gA;
  const int nB = 40 + a0;
  int grp, j_;
  if (k < nB) { grp = gA + 1; j_ = k; }
  else        { grp = gA;     j_ = a0 + (k - nB); }
  const int qt  = 31 - j_ / 5;
  const int hh  = j_ % 5;
  const int b   = grp / 5;
  const int kvh = grp % 5;
  const int h   = kvh * 5 + hh;
  const int qb  = qt * QB;
  const int tid = threadIdx.x, wid = tid >> 6, lane = tid & 63;
  const int l15 = lane & 15, g = lane >> 4;
  const int qrow0 = wid * 16;

  __shared__ u32 Ks[TILE_U32];           // K tile, single-buffered
  __shared__ u32 Vt[TILE_U32];           // V^T tile, single-buffered (Q staging pre-loop)

  const int nt    = (qt <= 18) ? (qt + 1) : 19;
  const int shift = qt - 18;

  const size_t kvbase = ((size_t)(b * N_KV + kvh)) * NTILES * TILE_U32;
  const u32* kb = kws + kvbase;
  const u32* vb = vws + kvbase;

  // ---- prologue: issue K(0)->Ks only (Vt hosts Q staging first) ----
  #pragma unroll
  for (int j = 0; j < 2; ++j) {
    int ci = (wid << 1) | j;             // 8 chunks, 2 per wave
    gload16(kb + ci * 256 + lane * 4, &Ks[ci * 256]);
  }

  // ---- Q staging into Vt, 4-rows-parallel: lane (g,l15) row 4it+g, d=4*l15..+3 ----
  {
    const int   jbase = (4 * l15) & 31;
    const float r32   = 0.74989420933f;            // 10000^(-1/32)
    float fr[4];
    fr[0] = powf(10000.f, -(float)jbase * (1.f / 32.f));
    fr[1] = fr[0] * r32; fr[2] = fr[1] * r32; fr[3] = fr[2] * r32;

    const int t0g = b * T_ + qb + qrow0;
    int pos_prev = pos_ids[t0g + g];
    float cc[4], sn[4], c4[4], s4[4];
    #pragma unroll
    for (int e = 0; e < 4; ++e) {
      sincosf((float)pos_prev * fr[e], &sn[e], &cc[e]);   // sincosf(x, sin*, cos*)
      sincosf(4.f * fr[e], &s4[e], &c4[e]);
    }
    const float4 wv = *(const float4*)&q_w[4 * l15];
    #pragma unroll
    for (int it = 0; it < 4; ++it) {
      const int row = 4 * it + g;
      if (it) {
        int pos = pos_ids[t0g + row];
        if (__all(pos == pos_prev + 4)) {
          #pragma unroll
          for (int e = 0; e < 4; ++e) {
            float c2 = cc[e] * c4[e] - sn[e] * s4[e];
            sn[e] = sn[e] * c4[e] + cc[e] * s4[e];
            cc[e] = c2;
          }
        } else {
          #pragma unroll
          for (int e = 0; e < 4; ++e) sincosf((float)pos * fr[e], &sn[e], &cc[e]);
        }
        pos_prev = pos;
      }
      const float4 xv = *(const float4*)&q_in[((size_t)(t0g + row)) * (N_HEADS * HEAD_DIM) + h * HEAD_DIM + 4 * l15];
      float ss = xv.x * xv.x + xv.y * xv.y + xv.z * xv.z + xv.w * xv.w;
      ss += __shfl_xor(ss, 1); ss += __shfl_xor(ss, 2);
      ss += __shfl_xor(ss, 4); ss += __shfl_xor(ss, 8);
      const float rn = rsqrtf(ss * (1.f / 64.f) + 1e-6f);
      float y[4] = {wv.x * xv.x * rn, wv.y * xv.y * rn, wv.z * xv.z * rn, wv.w * xv.w * rn};
      float rv[4];
      #pragma unroll
      for (int e = 0; e < 4; ++e) {
        float part = __shfl_xor(y[e], 8);
        rv[e] = ((l15 < 8) ? (y[e] * cc[e] - part * sn[e])
                           : (y[e] * cc[e] + part * sn[e])) * 0.18033688f;
      }
      u32x2 w2;
      w2.x = pack2(rv[0], rv[1]);
      w2.y = pack2(rv[2], rv[3]);
      *(u32x2*)&Vt[(qrow0 + row) * 32 + 2 * l15] = w2;
    }
  }
  __syncthreads();                       // K(0) drained + Q rows visible in Vt

  bf16x8 qf[2];
  #pragma unroll
  for (int ks = 0; ks < 2; ++ks)
    qf[ks] = *(const bf16x8*)&Vt[(qrow0 + l15) * 32 + 16 * ks + 4 * g];
  __syncthreads();                       // all qf reads done -> Vt free for V(0)

  // ---- issue V(0) into Vt (drained by tile-0 mid-barrier under QK^T+softmax) ----
  #pragma unroll
  for (int j = 0; j < 2; ++j) {
    int ci = (wid << 1) | j;
    gload16(vb + ci * 256 + lane * 4, &Vt[ci * 256]);
  }

  f32x4 acc_o[4];
  #pragma unroll
  for (int mt = 0; mt < 4; ++mt) acc_o[mt] = (f32x4)(0.f);
  f32x4 acc_l = (f32x4)(0.f);            // l by MFMA: P x ones -> row q, replicated cols

  u32x4 onesw;
  onesw.x = 0x3F803F80u; onesw.y = 0x3F803F80u; onesw.z = 0x3F803F80u; onesw.w = 0x3F803F80u;
  const bf16x8 vones = __builtin_bit_cast(bf16x8, onesw);

  const int q_abs = qb + qrow0 + l15;

  for (int i2 = 0; i2 < nt; ++i2) {
    const int k0 = ((qt <= 18 || i2 < 2) ? i2 : i2 + shift) << 6;
    int tn = -1;
    if (i2 + 1 < nt) tn = (qt <= 18 || i2 + 1 < 2) ? (i2 + 1) : (i2 + 1 + shift);

    // ---- S^T - 20 = K·Q^T + C(-20)  (reads Ks = K(i2)) ----
    f32x4 accs[4];
    #pragma unroll
    for (int mt = 0; mt < 4; ++mt) accs[mt] = (f32x4)(SM_BIAS);
    #pragma unroll
    for (int ks = 0; ks < 2; ++ks) {
      #pragma unroll
      for (int mt = 0; mt < 4; ++mt) {
        bf16x8 kf = *(const bf16x8*)&Ks[(16 * mt + l15) * 32 + (((4 * ks + g) ^ (l15 & 7)) << 2)];
        accs[mt] = __builtin_amdgcn_mfma_f32_16x16x32_bf16(kf, qf[ks], accs[mt], 0, 0, 0);
      }
    }

    // ---- mask boundary tiles, then P = exp2(S - 20) ----
    const bool do_mask = (i2 == nt - 1) || (qt >= 18 && i2 == 2);
    if (do_mask) {
      #pragma unroll
      for (int mt = 0; mt < 4; ++mt)
        #pragma unroll
        for (int rg = 0; rg < 4; ++rg) {
          int key = k0 + 16 * mt + 4 * g + rg;
          bool ok = (key <= q_abs) && ((key >= q_abs - (WINDOW - 1)) || (key < N_META));
          accs[mt][rg] = ok ? accs[mt][rg] : -INFINITY;
        }
    }
    #pragma unroll
    for (int mt = 0; mt < 4; ++mt)
      #pragma unroll
      for (int rg = 0; rg < 4; ++rg)
        accs[mt][rg] = fexp2(accs[mt][rg]);      // exp2(-inf) = 0 for masked

    // ---- mid-barrier: drains V(i2) (issued ~1 phase earlier) ----
    __syncthreads();

    // ---- issue K(i2+1) into Ks (all QK^T reads of K(i2) done across waves) ----
    if (tn >= 0) {
      const u32* kt = kb + (size_t)tn * TILE_U32;
      #pragma unroll
      for (int j = 0; j < 2; ++j) {
        int ci = (wid << 1) | j;
        gload16(kt + ci * 256 + lane * 4, &Ks[ci * 256]);
      }
    }

    // ---- O += P·V, l += P·1 (reads Vt = V(i2)) ----
    #pragma unroll
    for (int ks2 = 0; ks2 < 2; ++ks2) {
      const int m0 = 2 * ks2, m1 = 2 * ks2 + 1;
      u32x4 aw;
      aw.x = pack2(accs[m0][0], accs[m0][1]);
      aw.y = pack2(accs[m0][2], accs[m0][3]);
      aw.z = pack2(accs[m1][0], accs[m1][1]);
      aw.w = pack2(accs[m1][2], accs[m1][3]);
      bf16x8 af = __builtin_bit_cast(bf16x8, aw);
      acc_l = __builtin_amdgcn_mfma_f32_16x16x32_bf16(af, vones, acc_l, 0, 0, 0);
      #pragma unroll
      for (int mt2 = 0; mt2 < 4; ++mt2) {
        bf16x8 vf = *(const bf16x8*)&Vt[(16 * mt2 + l15) * 32 + (((4 * ks2 + g) ^ (l15 & 7)) << 2)];
        acc_o[mt2] = __builtin_amdgcn_mfma_f32_16x16x32_bf16(af, vf, acc_o[mt2], 0, 0, 0);
      }
    }

    __syncthreads();     // end-barrier: drains K(i2+1); all V(i2) reads done

    // ---- issue V(i2+1) into Vt (drained by next mid-barrier) ----
    if (tn >= 0) {
      const u32* vt = vb + (size_t)tn * TILE_U32;
      #pragma unroll
      for (int j = 0; j < 2; ++j) {
        int ci = (wid << 1) | j;
        gload16(vt + ci * 256 + lane * 4, &Vt[ci * 256]);
      }
    }
  }

  // ---- epilogue: l4[rg] = acc_l[rg] directly (row q'=4g+rg, replicated over cols) ----
  #pragma unroll
  for (int mt2 = 0; mt2 < 4; ++mt2)
    #pragma unroll
    for (int rg = 0; rg < 4; ++rg) {
      int t = qb + qrow0 + 4 * g + rg;
      out[((size_t)(b * T_ + t)) * (N_HEADS * HEAD_DIM) + h * HEAD_DIM + 16 * mt2 + l15] =
          acc_o[mt2][rg] / acc_l[rg];
    }
}

extern "C" void kernel_launch(void* const* d_in, const int* in_sizes, int n_in,
                              void* d_out, int out_size, void* d_ws, size_t ws_size,
                              hipStream_t stream) {
  const float* q   = (const float*)d_in[0];
  const float* k   = (const float*)d_in[1];
  const float* v   = (const float*)d_in[2];
  const float* qw  = (const float*)d_in[3];
  const float* kw  = (const float*)d_in[4];
  const int*   pos = (const int*)d_in[5];

  u32* kp = (u32*)d_ws;                                    // 2.62 MB
  u32* vp = kp + (size_t)B_ * N_KV * NTILES * TILE_U32;    // 2.62 MB
  float* outp = (float*)d_out;

  // merged prep: 320 V-tile blocks + 320 K-wave blocks (16 rows/wave) in one launch
  prep_kernel<<<2 * B_ * N_KV * NTILES, 256, 0, stream>>>(k, kw, v, pos, kp, vp);
  attn_kernel<<<1600, 256, 0, stream>>>(q, qw, pos, kp, vp, outp);
}